// Round 13
// baseline (397.483 us; speedup 1.0000x reference)
//
#include <hip/hip_runtime.h>
#include <hip/hip_bf16.h>

#pragma clang fp contract(off)

#define NN 8192
#define NE 131072
#define DIN 256
#define DH 32
#define DL 64

typedef unsigned int u32;

struct Key { u32 a, b; };

__device__ __forceinline__ u32 rotl32(u32 x, int d) { return (x << d) | (x >> (32 - d)); }

// JAX threefry2x32: 20 rounds, 5 key injections.
__device__ __forceinline__ void tf2x32(u32 k0, u32 k1, u32& x0, u32& x1) {
  u32 k2 = k0 ^ k1 ^ 0x1BD11BDAu;
  x0 += k0; x1 += k1;
  x0 += x1; x1 = rotl32(x1, 13); x1 ^= x0;
  x0 += x1; x1 = rotl32(x1, 15); x1 ^= x0;
  x0 += x1; x1 = rotl32(x1, 26); x1 ^= x0;
  x0 += x1; x1 = rotl32(x1, 6);  x1 ^= x0;
  x0 += k1; x1 += k2 + 1u;
  x0 += x1; x1 = rotl32(x1, 17); x1 ^= x0;
  x0 += x1; x1 = rotl32(x1, 29); x1 ^= x0;
  x0 += x1; x1 = rotl32(x1, 16); x1 ^= x0;
  x0 += x1; x1 = rotl32(x1, 24); x1 ^= x0;
  x0 += k2; x1 += k0 + 2u;
  x0 += x1; x1 = rotl32(x1, 13); x1 ^= x0;
  x0 += x1; x1 = rotl32(x1, 15); x1 ^= x0;
  x0 += x1; x1 = rotl32(x1, 26); x1 ^= x0;
  x0 += x1; x1 = rotl32(x1, 6);  x1 ^= x0;
  x0 += k0; x1 += k1 + 3u;
  x0 += x1; x1 = rotl32(x1, 17); x1 ^= x0;
  x0 += x1; x1 = rotl32(x1, 29); x1 ^= x0;
  x0 += x1; x1 = rotl32(x1, 16); x1 ^= x0;
  x0 += x1; x1 = rotl32(x1, 24); x1 ^= x0;
  x0 += k1; x1 += k2 + 4u;
  x0 += x1; x1 = rotl32(x1, 13); x1 ^= x0;
  x0 += x1; x1 = rotl32(x1, 15); x1 ^= x0;
  x0 += x1; x1 = rotl32(x1, 26); x1 ^= x0;
  x0 += x1; x1 = rotl32(x1, 6);  x1 ^= x0;
  x0 += k2; x1 += k0 + 5u;
}

// jax_threefry_partitionable: split(key,n)[i] == fold_in(key,i) == block (0,i).
__device__ __forceinline__ Key fold(Key k, u32 i) {
  u32 x0 = 0u, x1 = i; tf2x32(k.a, k.b, x0, x1);
  Key r; r.a = x0; r.b = x1; return r;
}
__device__ __forceinline__ u32 pbits(Key k, u32 i) {
  u32 x0 = 0u, x1 = i; tf2x32(k.a, k.b, x0, x1);
  return x0 ^ x1;
}

// ---- XLA CPU transcendentals (Cephes, FMA'd) ----

__device__ __forceinline__ float xla_logf(float x) {
  if (x == 0.0f) return -__builtin_huge_valf();
  u32 bits = __float_as_uint(x);
  float ef = (float)((int)(bits >> 23) - 126);
  float m = __uint_as_float((bits & 0x007fffffu) | 0x3f000000u);
  if (m < 0.707106781186547524f) { ef = ef - 1.0f; m = m + m; }
  m = m - 1.0f;
  float z = m * m;
  float y = 7.0376836292e-2f;
  y = fmaf(y, m, -1.1514610310e-1f);
  y = fmaf(y, m, 1.1676998740e-1f);
  y = fmaf(y, m, -1.2420140846e-1f);
  y = fmaf(y, m, 1.4249322787e-1f);
  y = fmaf(y, m, -1.6668057665e-1f);
  y = fmaf(y, m, 2.0000714765e-1f);
  y = fmaf(y, m, -2.4999993993e-1f);
  y = fmaf(y, m, 3.3333331174e-1f);
  y = y * m;
  y = y * z;
  y = fmaf(ef, -2.12194440e-4f, y);
  y = fmaf(-0.5f, z, y);
  float r = m + y;
  r = fmaf(ef, 0.693359375f, r);
  return r;
}

__device__ __forceinline__ float xla_expf(float x) {
  x = fminf(x, 88.3762626647950f);
  x = fmaxf(x, -88.3762626647949f);
  float fx = fmaf(x, 1.44269504088896341f, 0.5f);
  fx = floorf(fx);
  x = fmaf(-fx, 0.693359375f, x);
  x = fmaf(fx, 2.12194440e-4f, x);
  float z = x * x;
  float y = 1.9875691500e-4f;
  y = fmaf(y, x, 1.3981999507e-3f);
  y = fmaf(y, x, 8.3334519073e-3f);
  y = fmaf(y, x, 4.1665795894e-2f);
  y = fmaf(y, x, 1.6666665459e-1f);
  y = fmaf(y, x, 5.0000001201e-1f);
  y = fmaf(y, z, x);
  y = y + 1.0f;
  int n = (int)fx;
  float p2n = __uint_as_float((u32)(n + 127) << 23);
  return y * p2n;
}

__device__ __forceinline__ float xla_log1pf(float x) {
  float u = x + 1.0f;
  if (u == 1.0f) return x;
  return xla_logf(u) * (x / (u - 1.0f));
}

__device__ __forceinline__ float u01_from_bits(u32 b) {
  return __uint_as_float((b >> 9) | 0x3f800000u) - 1.0f;
}
__device__ __forceinline__ float jax_uniform_scalar(Key k) {
  float f = u01_from_bits(pbits(k, 0u));
  return fmaxf(0.0f, f);
}

__device__ __forceinline__ float erfinv_f32(float x) {
  float w = -xla_log1pf(-(x * x));
  float p;
  if (w < 5.0f) {
    w = w - 2.5f;
    p = 2.81022636e-08f;
    p = fmaf(p, w, 3.43273939e-07f);
    p = fmaf(p, w, -3.5233877e-06f);
    p = fmaf(p, w, -4.39150654e-06f);
    p = fmaf(p, w, 0.00021858087f);
    p = fmaf(p, w, -0.00125372503f);
    p = fmaf(p, w, -0.00417768164f);
    p = fmaf(p, w, 0.246640727f);
    p = fmaf(p, w, 1.50140941f);
  } else {
    w = sqrtf(w) - 3.0f;
    p = -0.000200214257f;
    p = fmaf(p, w, 0.000100950558f);
    p = fmaf(p, w, 0.00134934322f);
    p = fmaf(p, w, -0.00367342844f);
    p = fmaf(p, w, 0.00573950773f);
    p = fmaf(p, w, -0.0076224613f);
    p = fmaf(p, w, 0.00943887047f);
    p = fmaf(p, w, 1.00167406f);
    p = fmaf(p, w, 2.83297682f);
  }
  return p * x;
}

__device__ __forceinline__ float normal_from_bits(u32 b) {
  float f = u01_from_bits(b);
  const float lo = -0.99999994f;
  float u = fmaxf(lo, fmaf(f, 2.0f, lo));
  return 1.4142135623730951f * erfinv_f32(u);
}

// jax _gamma_one, alpha=31.5, log_space=True — f32.
// FIXED (r13): Marsaglia-Tsang c = 1/sqrt(9d)  [was (1/3)/sqrt(9d): 3x too
// small => gamma variance 9x too small => every eps/w distorted => the
// persistent 0.2102 absmax across rounds 2-12].
__device__ float loggamma31_5(Key k) {
  const float dd = 31.5f - (1.0f / 3.0f);
  const float cc = 1.0f / sqrtf(9.0f * dd);
  Key key = fold(k, 0u);
  float X = 0.0f, V = 1.0f, U = 2.0f;
  for (int it = 0; it < 64; ++it) {
    bool c1 = U >= fmaf(-0.0331f, X * X, 1.0f);
    bool c2 = xla_logf(U) >= fmaf(dd, (1.0f - V) + xla_logf(V), X * 0.5f);
    if (!(c1 && c2)) break;
    Key xk = fold(key, 1u);
    Key Uk = fold(key, 2u);
    key = fold(key, 0u);
    float x = 0.0f, v = -1.0f;
    for (int j = 0; j < 32 && v <= 0.0f; ++j) {
      Key sk = fold(xk, 1u);
      xk = fold(xk, 0u);
      x = normal_from_bits(pbits(sk, 0u));
      v = fmaf(x, cc, 1.0f);
    }
    X = x * x; V = (v * v) * v;
    U = jax_uniform_scalar(Uk);
  }
  return xla_logf(V) + xla_logf(dd);
}

__device__ __forceinline__ float wave_sum(float v) {
  for (int d = 1; d < 64; d <<= 1) v += __shfl_xor(v, d, 64);
  return v;
}

// ---------------- graph / GCN kernels ----------------

__global__ void count_k(const int* __restrict__ ei, u32* __restrict__ cnt) {
  int e = blockIdx.x * blockDim.x + threadIdx.x;
  if (e < NE) atomicAdd(&cnt[ei[NE + e]], 1u);
}

__global__ void scan_k(const u32* __restrict__ cnt, u32* __restrict__ off, float* __restrict__ dinv) {
  __shared__ u32 part[256];
  int t = threadIdx.x;
  int base = t * 32;
  u32 s = 0;
  for (int i = 0; i < 32; ++i) s += cnt[base + i];
  part[t] = s;
  __syncthreads();
  if (t == 0) {
    u32 acc = 0;
    for (int i = 0; i < 256; ++i) { u32 v = part[i]; part[i] = acc; acc += v; }
  }
  __syncthreads();
  u32 acc = part[t];
  for (int i = 0; i < 32; ++i) {
    off[base + i] = acc;
    u32 c = cnt[base + i];
    acc += c;
    dinv[base + i] = 1.0f / sqrtf((float)(c + 1u));
  }
  if (t == 255) off[NN] = acc;
}

__global__ void fill_k(const int* __restrict__ ei, const u32* __restrict__ off,
                       u32* __restrict__ fl, u32* __restrict__ csr) {
  int e = blockIdx.x * blockDim.x + threadIdx.x;
  if (e < NE) {
    int d = ei[NE + e];
    u32 p = off[d] + atomicAdd(&fl[d], 1u);
    csr[p] = (u32)e;
  }
}

__global__ void sort_k(const u32* __restrict__ off, u32* __restrict__ csr) {
  int n = blockIdx.x * blockDim.x + threadIdx.x;
  if (n >= NN) return;
  u32 s = off[n], e2 = off[n + 1];
  for (u32 i = s + 1; i < e2; ++i) {
    u32 v = csr[i]; u32 j = i;
    while (j > s && csr[j - 1] > v) { csr[j] = csr[j - 1]; --j; }
    csr[j] = v;
  }
}

__global__ __launch_bounds__(256) void mm_xw1_k(const float* __restrict__ X,
                                                const float* __restrict__ W1,
                                                float* __restrict__ XW) {
  __shared__ float w[DIN * DH];
  for (int i = threadIdx.x; i < DIN * DH; i += 256) w[i] = W1[i];
  __syncthreads();
  int f = threadIdx.x & 31, r0 = threadIdx.x >> 5;
  int base = blockIdx.x * 32;
  for (int pass = 0; pass < 4; ++pass) {
    int r = base + r0 + pass * 8;
    const float4* xr = reinterpret_cast<const float4*>(X + (size_t)r * DIN);
    float acc = 0.0f;
    for (int k4 = 0; k4 < DIN / 4; ++k4) {
      float4 xv = xr[k4];
      int k = k4 * 4;
      acc = fmaf(xv.x, w[(k + 0) * DH + f], acc);
      acc = fmaf(xv.y, w[(k + 1) * DH + f], acc);
      acc = fmaf(xv.z, w[(k + 2) * DH + f], acc);
      acc = fmaf(xv.w, w[(k + 3) * DH + f], acc);
    }
    XW[(size_t)r * DH + f] = acc;
  }
}

__global__ void agg_h_k(const float* __restrict__ XW, const u32* __restrict__ off,
                        const u32* __restrict__ csr, const int* __restrict__ ei,
                        const float* __restrict__ dinv, const float* __restrict__ b1,
                        float* __restrict__ H) {
  int idx = blockIdx.x * blockDim.x + threadIdx.x;
  int n = idx >> 5, f = idx & 31;
  if (n >= NN) return;
  float dn = dinv[n];
  float acc = 0.0f;
  u32 s0 = off[n], s1 = off[n + 1];
  for (u32 p = s0; p < s1; ++p) {
    int e = (int)csr[p];
    int s = ei[e];
    acc += XW[s * DH + f] * (dinv[s] * dn);
  }
  acc += XW[n * DH + f] * (dn * dn);
  acc += b1[f];
  H[n * DH + f] = fmaxf(acc, 0.0f);
}

__global__ void mm_h_k(const float* __restrict__ H, const float* __restrict__ Wmu,
                       const float* __restrict__ Wk, float* __restrict__ HWmu,
                       float* __restrict__ HWk) {
  __shared__ float wm[DH * DL];
  __shared__ float wk[DH];
  for (int i = threadIdx.x; i < DH * DL; i += 256) wm[i] = Wmu[i];
  if (threadIdx.x < DH) wk[threadIdx.x] = Wk[threadIdx.x];
  __syncthreads();
  int f = threadIdx.x & 63, l = threadIdx.x >> 6;
  int n = blockIdx.x * 4 + l;
  const float* h = H + n * DH;
  float acc = 0.0f;
  for (int k = 0; k < DH; ++k) acc = fmaf(h[k], wm[k * DL + f], acc);
  HWmu[(size_t)n * DL + f] = acc;
  if (f == 0) {
    float a2 = 0.0f;
    for (int k = 0; k < DH; ++k) a2 = fmaf(h[k], wk[k], a2);
    HWk[n] = a2;
  }
}

__global__ void agg_mu_k(const float* __restrict__ HW, const u32* __restrict__ off,
                         const u32* __restrict__ csr, const int* __restrict__ ei,
                         const float* __restrict__ dinv, const float* __restrict__ bmu,
                         float* __restrict__ out) {
  int idx = blockIdx.x * blockDim.x + threadIdx.x;
  int n = idx >> 6, f = idx & 63;
  if (n >= NN) return;
  float dn = dinv[n], acc = 0.0f;
  for (u32 p = off[n]; p < off[n + 1]; ++p) {
    int e = (int)csr[p]; int s = ei[e];
    acc += HW[(size_t)s * DL + f] * (dinv[s] * dn);
  }
  acc += HW[(size_t)n * DL + f] * (dn * dn);
  out[(size_t)n * DL + f] = acc + bmu[f];
}

__global__ void agg_kap_k(const float* __restrict__ HWk, const u32* __restrict__ off,
                          const u32* __restrict__ csr, const int* __restrict__ ei,
                          const float* __restrict__ dinv, const float* __restrict__ bk,
                          float* __restrict__ kap, float* __restrict__ outKA) {
  int n = blockIdx.x * blockDim.x + threadIdx.x;
  if (n >= NN) return;
  float dn = dinv[n], acc = 0.0f;
  for (u32 p = off[n]; p < off[n + 1]; ++p) {
    int e = (int)csr[p]; int s = ei[e];
    acc += HWk[s] * (dinv[s] * dn);
  }
  acc += HWk[n] * (dn * dn);
  acc += bk[0];
  float sp = fmaxf(acc, 0.0f) + xla_log1pf(xla_expf(-fabsf(acc)));
  kap[n] = sp; outKA[n] = sp;
}

__global__ void norm_mus_k(const float* __restrict__ musraw, float* __restrict__ mus,
                           float* __restrict__ outMU) {
  int gid = blockIdx.x * blockDim.x + threadIdx.x;
  int n = gid >> 6, lane = threadIdx.x & 63;
  if (n >= NN) return;
  float v = musraw[(size_t)n * DL + lane];
  float nm = sqrtf(wave_sum(v * v)) + 1e-12f;
  float r = v / nm;
  mus[(size_t)n * DL + lane] = r;
  outMU[(size_t)n * DL + lane] = r;
}

// ---------------- sampling kernels ----------------

__global__ void build_keys_k(u32* __restrict__ ktab) {
  if (threadIdx.x != 0 || blockIdx.x != 0) return;
  Key root; root.a = 0u; root.b = 42u;
  Key kw = fold(root, 0u);
  Key kv = fold(root, 1u);
  ktab[192] = kv.a; ktab[193] = kv.b;
  for (int t = 0; t < 32; ++t) {
    Key kt = fold(kw, (u32)t);
    Key kb = fold(kt, 0u);
    Key ku = fold(kt, 1u);
    Key ka = fold(kb, 0u);
    Key kbb = fold(kb, 1u);
    ktab[6 * t + 0] = ka.a;  ktab[6 * t + 1] = ka.b;
    ktab[6 * t + 2] = kbb.a; ktab[6 * t + 3] = kbb.b;
    ktab[6 * t + 4] = ku.a;  ktab[6 * t + 5] = ku.b;
  }
}

__global__ void sample_w_k(const float* __restrict__ kap, const u32* __restrict__ ktab,
                           float* __restrict__ wv) {
  int n = blockIdx.x * blockDim.x + threadIdx.x;
  if (n >= NN) return;
  float kappa = kap[n];
  float kk = kappa * kappa;
  float s  = sqrtf(fmaf(4.0f, kk, 3969.0f));
  float bb = fmaf(-2.0f, kappa, s) / 63.0f;
  float aa = (fmaf(2.0f, kappa, 63.0f) + s) / 4.0f;
  float dd = (4.0f * aa) * bb / (1.0f + bb) - 261.01748776266657f;  // 63*log(63)
  float w = 0.0f;
  for (int t = 0; t < 32; ++t) {
    const u32* kt = ktab + 6 * t;
    Key ka; ka.a = kt[0]; ka.b = kt[1];
    Key kb; kb.a = kt[2]; kb.b = kt[3];
    Key ku; ku.a = kt[4]; ku.b = kt[5];
    Key sa = fold(ka, (u32)n);
    Key sb = fold(kb, (u32)n);
    float lga = loggamma31_5(sa);
    float lgb = loggamma31_5(sb);
    float mx = fmaxf(lga, lgb);
    float ea = xla_expf(lga - mx), eb = xla_expf(lgb - mx);
    float eps = ea / (ea + eb);
    float u = fmaxf(0.0f, u01_from_bits(pbits(ku, (u32)n)));
    float denom = fmaf(-(1.0f - bb), eps, 1.0f);
    w = fmaf(-(1.0f + bb), eps, 1.0f) / denom;
    float tt = (2.0f * aa) * bb / denom;
    float lt = xla_logf(tt);
    float margin = fmaf(63.0f, lt, -tt) + dd;
    if (margin >= xla_logf(u)) break;
  }
  wv[n] = w;
}

__global__ void z_k(const float* __restrict__ mus, const float* __restrict__ wv,
                    const u32* __restrict__ ktab, float* __restrict__ Z) {
  int gid = blockIdx.x * blockDim.x + threadIdx.x;
  int n = gid >> 6, lane = threadIdx.x & 63;
  if (n >= NN) return;
  Key kv; kv.a = ktab[192]; kv.b = ktab[193];
  float vj = 0.0f;
  if (lane >= 1) {
    u32 idx = (u32)(n * 63 + (lane - 1));
    vj = normal_from_bits(pbits(kv, idx));
  }
  float vn = sqrtf(wave_sum(vj * vj));
  vj = vj / vn;
  float w = wv[n];
  float zj = (lane == 0) ? w : sqrtf(fmaxf(1.0f - w * w, 0.0f)) * vj;
  float mu = mus[(size_t)n * DL + lane];
  float uh = ((lane == 0) ? 1.0f : 0.0f) - mu;
  float un = sqrtf(wave_sum(uh * uh)) + 1e-8f;
  uh = uh / un;
  float dot = wave_sum(zj * uh);
  Z[(size_t)n * DL + lane] = zj - 2.0f * dot * uh;
}

// ---------------- ZZt GEMM ----------------

__global__ __launch_bounds__(256) void zzt_k(const float* __restrict__ Z, float* __restrict__ out) {
#pragma clang fp contract(fast)
  __shared__ float As[64][65];
  __shared__ float Bs[64][65];
  int bi = blockIdx.y, bj = blockIdx.x;
  for (int i = threadIdx.x; i < 4096; i += 256) {
    int r = i >> 6, c = i & 63;
    As[r][c] = Z[((size_t)(bi * 64 + r)) * 64 + c];
    Bs[r][c] = Z[((size_t)(bj * 64 + r)) * 64 + c];
  }
  __syncthreads();
  int tx = threadIdx.x & 15, ty = threadIdx.x >> 4;
  float acc[4][4];
#pragma unroll
  for (int ii = 0; ii < 4; ++ii)
#pragma unroll
    for (int jj = 0; jj < 4; ++jj) acc[ii][jj] = 0.0f;
  for (int k = 0; k < 64; ++k) {
    float av[4], bv[4];
#pragma unroll
    for (int ii = 0; ii < 4; ++ii) av[ii] = As[ty * 4 + ii][k];
#pragma unroll
    for (int jj = 0; jj < 4; ++jj) bv[jj] = Bs[tx * 4 + jj][k];
#pragma unroll
    for (int ii = 0; ii < 4; ++ii)
#pragma unroll
      for (int jj = 0; jj < 4; ++jj) acc[ii][jj] += av[ii] * bv[jj];
  }
#pragma unroll
  for (int ii = 0; ii < 4; ++ii) {
    int r = bi * 64 + ty * 4 + ii;
    float4 v0 = make_float4(acc[ii][0], acc[ii][1], acc[ii][2], acc[ii][3]);
    *reinterpret_cast<float4*>(&out[(size_t)r * NN + bj * 64 + tx * 4]) = v0;
  }
}

// ---------------- launch ----------------

extern "C" void kernel_launch(void* const* d_in, const int* in_sizes, int n_in,
                              void* d_out, int out_size, void* d_ws, size_t ws_size,
                              hipStream_t stream) {
  const float* X   = (const float*)d_in[0];
  const int*   ei  = (const int*)d_in[1];
  const float* W1  = (const float*)d_in[2];
  const float* b1  = (const float*)d_in[3];
  const float* Wmu = (const float*)d_in[4];
  const float* bmu = (const float*)d_in[5];
  const float* Wk  = (const float*)d_in[6];
  const float* bk  = (const float*)d_in[7];

  char* wp = (char*)d_ws;
  auto alloc = [&](size_t bytes) -> char* {
    char* p = wp; wp += (bytes + 255) & ~(size_t)255; return p;
  };
  u32* cnt    = (u32*)alloc((size_t)NN * 4);
  u32* fill   = (u32*)alloc((size_t)NN * 4);
  u32* off    = (u32*)alloc((size_t)(NN + 1) * 4);
  u32* csr    = (u32*)alloc((size_t)NE * 4);
  u32* ktab   = (u32*)alloc(256 * 4);
  float* dinv = (float*)alloc((size_t)NN * 4);
  float* XW1  = (float*)alloc((size_t)NN * DH * 4);
  float* H    = (float*)alloc((size_t)NN * DH * 4);
  float* HWmu = (float*)alloc((size_t)NN * DL * 4);
  float* HWk  = (float*)alloc((size_t)NN * 4);
  float* musr = (float*)alloc((size_t)NN * DL * 4);
  float* mus  = (float*)alloc((size_t)NN * DL * 4);
  float* kap  = (float*)alloc((size_t)NN * 4);
  float* wv   = (float*)alloc((size_t)NN * 4);
  float* Z    = (float*)alloc((size_t)NN * DL * 4);

  float* outZZ = (float*)d_out;
  float* outMU = outZZ + (size_t)NN * NN;
  float* outKA = outMU + (size_t)NN * DL;

  hipMemsetAsync(cnt, 0, (size_t)NN * 4, stream);
  hipMemsetAsync(fill, 0, (size_t)NN * 4, stream);
  build_keys_k<<<1, 64, 0, stream>>>(ktab);
  count_k<<<NE / 256, 256, 0, stream>>>(ei, cnt);
  scan_k<<<1, 256, 0, stream>>>(cnt, off, dinv);
  fill_k<<<NE / 256, 256, 0, stream>>>(ei, off, fill, csr);
  sort_k<<<NN / 256, 256, 0, stream>>>(off, csr);
  mm_xw1_k<<<NN / 32, 256, 0, stream>>>(X, W1, XW1);
  agg_h_k<<<NN * DH / 256, 256, 0, stream>>>(XW1, off, csr, ei, dinv, b1, H);
  mm_h_k<<<NN / 4, 256, 0, stream>>>(H, Wmu, Wk, HWmu, HWk);
  agg_mu_k<<<NN * DL / 256, 256, 0, stream>>>(HWmu, off, csr, ei, dinv, bmu, musr);
  agg_kap_k<<<NN / 256, 256, 0, stream>>>(HWk, off, csr, ei, dinv, bk, kap, outKA);
  norm_mus_k<<<NN * DL / 256, 256, 0, stream>>>(musr, mus, outMU);
  sample_w_k<<<NN / 256, 256, 0, stream>>>(kap, ktab, wv);
  z_k<<<NN * DL / 256, 256, 0, stream>>>(mus, wv, ktab, Z);
  dim3 g(128, 128);
  zzt_k<<<g, 256, 0, stream>>>(Z, outZZ);
}

// Round 14
// 270.086 us; speedup vs baseline: 1.4717x; 1.4717x over previous
//
#include <hip/hip_runtime.h>
#include <hip/hip_bf16.h>

#pragma clang fp contract(off)

#define NN 8192
#define NE 131072
#define DIN 256
#define DH 32
#define DL 64

typedef unsigned int u32;
typedef __bf16 bf16x8 __attribute__((ext_vector_type(8)));
typedef float f32x4 __attribute__((ext_vector_type(4)));

struct Key { u32 a, b; };

__device__ __forceinline__ u32 rotl32(u32 x, int d) { return (x << d) | (x >> (32 - d)); }

// JAX threefry2x32: 20 rounds, 5 key injections.
__device__ __forceinline__ void tf2x32(u32 k0, u32 k1, u32& x0, u32& x1) {
  u32 k2 = k0 ^ k1 ^ 0x1BD11BDAu;
  x0 += k0; x1 += k1;
  x0 += x1; x1 = rotl32(x1, 13); x1 ^= x0;
  x0 += x1; x1 = rotl32(x1, 15); x1 ^= x0;
  x0 += x1; x1 = rotl32(x1, 26); x1 ^= x0;
  x0 += x1; x1 = rotl32(x1, 6);  x1 ^= x0;
  x0 += k1; x1 += k2 + 1u;
  x0 += x1; x1 = rotl32(x1, 17); x1 ^= x0;
  x0 += x1; x1 = rotl32(x1, 29); x1 ^= x0;
  x0 += x1; x1 = rotl32(x1, 16); x1 ^= x0;
  x0 += x1; x1 = rotl32(x1, 24); x1 ^= x0;
  x0 += k2; x1 += k0 + 2u;
  x0 += x1; x1 = rotl32(x1, 13); x1 ^= x0;
  x0 += x1; x1 = rotl32(x1, 15); x1 ^= x0;
  x0 += x1; x1 = rotl32(x1, 26); x1 ^= x0;
  x0 += x1; x1 = rotl32(x1, 6);  x1 ^= x0;
  x0 += k0; x1 += k1 + 3u;
  x0 += x1; x1 = rotl32(x1, 17); x1 ^= x0;
  x0 += x1; x1 = rotl32(x1, 29); x1 ^= x0;
  x0 += x1; x1 = rotl32(x1, 16); x1 ^= x0;
  x0 += x1; x1 = rotl32(x1, 24); x1 ^= x0;
  x0 += k1; x1 += k2 + 4u;
  x0 += x1; x1 = rotl32(x1, 13); x1 ^= x0;
  x0 += x1; x1 = rotl32(x1, 15); x1 ^= x0;
  x0 += x1; x1 = rotl32(x1, 26); x1 ^= x0;
  x0 += x1; x1 = rotl32(x1, 6);  x1 ^= x0;
  x0 += k2; x1 += k0 + 5u;
}

// jax_threefry_partitionable: split(key,n)[i] == fold_in(key,i) == block (0,i).
__device__ __forceinline__ Key fold(Key k, u32 i) {
  u32 x0 = 0u, x1 = i; tf2x32(k.a, k.b, x0, x1);
  Key r; r.a = x0; r.b = x1; return r;
}
__device__ __forceinline__ u32 pbits(Key k, u32 i) {
  u32 x0 = 0u, x1 = i; tf2x32(k.a, k.b, x0, x1);
  return x0 ^ x1;
}

// ---- XLA CPU transcendentals (Cephes, FMA'd) ----

__device__ __forceinline__ float xla_logf(float x) {
  if (x == 0.0f) return -__builtin_huge_valf();
  u32 bits = __float_as_uint(x);
  float ef = (float)((int)(bits >> 23) - 126);
  float m = __uint_as_float((bits & 0x007fffffu) | 0x3f000000u);
  if (m < 0.707106781186547524f) { ef = ef - 1.0f; m = m + m; }
  m = m - 1.0f;
  float z = m * m;
  float y = 7.0376836292e-2f;
  y = fmaf(y, m, -1.1514610310e-1f);
  y = fmaf(y, m, 1.1676998740e-1f);
  y = fmaf(y, m, -1.2420140846e-1f);
  y = fmaf(y, m, 1.4249322787e-1f);
  y = fmaf(y, m, -1.6668057665e-1f);
  y = fmaf(y, m, 2.0000714765e-1f);
  y = fmaf(y, m, -2.4999993993e-1f);
  y = fmaf(y, m, 3.3333331174e-1f);
  y = y * m;
  y = y * z;
  y = fmaf(ef, -2.12194440e-4f, y);
  y = fmaf(-0.5f, z, y);
  float r = m + y;
  r = fmaf(ef, 0.693359375f, r);
  return r;
}

__device__ __forceinline__ float xla_expf(float x) {
  x = fminf(x, 88.3762626647950f);
  x = fmaxf(x, -88.3762626647949f);
  float fx = fmaf(x, 1.44269504088896341f, 0.5f);
  fx = floorf(fx);
  x = fmaf(-fx, 0.693359375f, x);
  x = fmaf(fx, 2.12194440e-4f, x);
  float z = x * x;
  float y = 1.9875691500e-4f;
  y = fmaf(y, x, 1.3981999507e-3f);
  y = fmaf(y, x, 8.3334519073e-3f);
  y = fmaf(y, x, 4.1665795894e-2f);
  y = fmaf(y, x, 1.6666665459e-1f);
  y = fmaf(y, x, 5.0000001201e-1f);
  y = fmaf(y, z, x);
  y = y + 1.0f;
  int n = (int)fx;
  float p2n = __uint_as_float((u32)(n + 127) << 23);
  return y * p2n;
}

__device__ __forceinline__ float xla_log1pf(float x) {
  float u = x + 1.0f;
  if (u == 1.0f) return x;
  return xla_logf(u) * (x / (u - 1.0f));
}

__device__ __forceinline__ float u01_from_bits(u32 b) {
  return __uint_as_float((b >> 9) | 0x3f800000u) - 1.0f;
}
__device__ __forceinline__ float jax_uniform_scalar(Key k) {
  float f = u01_from_bits(pbits(k, 0u));
  return fmaxf(0.0f, f);
}

__device__ __forceinline__ float erfinv_f32(float x) {
  float w = -xla_log1pf(-(x * x));
  float p;
  if (w < 5.0f) {
    w = w - 2.5f;
    p = 2.81022636e-08f;
    p = fmaf(p, w, 3.43273939e-07f);
    p = fmaf(p, w, -3.5233877e-06f);
    p = fmaf(p, w, -4.39150654e-06f);
    p = fmaf(p, w, 0.00021858087f);
    p = fmaf(p, w, -0.00125372503f);
    p = fmaf(p, w, -0.00417768164f);
    p = fmaf(p, w, 0.246640727f);
    p = fmaf(p, w, 1.50140941f);
  } else {
    w = sqrtf(w) - 3.0f;
    p = -0.000200214257f;
    p = fmaf(p, w, 0.000100950558f);
    p = fmaf(p, w, 0.00134934322f);
    p = fmaf(p, w, -0.00367342844f);
    p = fmaf(p, w, 0.00573950773f);
    p = fmaf(p, w, -0.0076224613f);
    p = fmaf(p, w, 0.00943887047f);
    p = fmaf(p, w, 1.00167406f);
    p = fmaf(p, w, 2.83297682f);
  }
  return p * x;
}

__device__ __forceinline__ float normal_from_bits(u32 b) {
  float f = u01_from_bits(b);
  const float lo = -0.99999994f;
  float u = fmaxf(lo, fmaf(f, 2.0f, lo));
  return 1.4142135623730951f * erfinv_f32(u);
}

// jax _gamma_one, alpha=31.5, log_space=True — f32. MT c = 1/sqrt(9d) (r13 fix).
__device__ float loggamma31_5(Key k) {
  const float dd = 31.5f - (1.0f / 3.0f);
  const float cc = 1.0f / sqrtf(9.0f * dd);
  Key key = fold(k, 0u);
  float X = 0.0f, V = 1.0f, U = 2.0f;
  for (int it = 0; it < 64; ++it) {
    bool c1 = U >= fmaf(-0.0331f, X * X, 1.0f);
    bool c2 = xla_logf(U) >= fmaf(dd, (1.0f - V) + xla_logf(V), X * 0.5f);
    if (!(c1 && c2)) break;
    Key xk = fold(key, 1u);
    Key Uk = fold(key, 2u);
    key = fold(key, 0u);
    float x = 0.0f, v = -1.0f;
    for (int j = 0; j < 32 && v <= 0.0f; ++j) {
      Key sk = fold(xk, 1u);
      xk = fold(xk, 0u);
      x = normal_from_bits(pbits(sk, 0u));
      v = fmaf(x, cc, 1.0f);
    }
    X = x * x; V = (v * v) * v;
    U = jax_uniform_scalar(Uk);
  }
  return xla_logf(V) + xla_logf(dd);
}

__device__ __forceinline__ float wave_sum(float v) {
  for (int d = 1; d < 64; d <<= 1) v += __shfl_xor(v, d, 64);
  return v;
}

// ---------------- graph / GCN kernels ----------------

__global__ void count_k(const int* __restrict__ ei, u32* __restrict__ cnt) {
  int e = blockIdx.x * blockDim.x + threadIdx.x;
  if (e < NE) atomicAdd(&cnt[ei[NE + e]], 1u);
}

__global__ void scan_k(const u32* __restrict__ cnt, u32* __restrict__ off, float* __restrict__ dinv) {
  __shared__ u32 part[256];
  int t = threadIdx.x;
  int base = t * 32;
  u32 s = 0;
  for (int i = 0; i < 32; ++i) s += cnt[base + i];
  part[t] = s;
  __syncthreads();
  if (t == 0) {
    u32 acc = 0;
    for (int i = 0; i < 256; ++i) { u32 v = part[i]; part[i] = acc; acc += v; }
  }
  __syncthreads();
  u32 acc = part[t];
  for (int i = 0; i < 32; ++i) {
    off[base + i] = acc;
    u32 c = cnt[base + i];
    acc += c;
    dinv[base + i] = 1.0f / sqrtf((float)(c + 1u));
  }
  if (t == 255) off[NN] = acc;
}

__global__ void fill_k(const int* __restrict__ ei, const u32* __restrict__ off,
                       u32* __restrict__ fl, u32* __restrict__ csr) {
  int e = blockIdx.x * blockDim.x + threadIdx.x;
  if (e < NE) {
    int d = ei[NE + e];
    u32 p = off[d] + atomicAdd(&fl[d], 1u);
    csr[p] = (u32)e;
  }
}

__global__ void sort_k(const u32* __restrict__ off, u32* __restrict__ csr) {
  int n = blockIdx.x * blockDim.x + threadIdx.x;
  if (n >= NN) return;
  u32 s = off[n], e2 = off[n + 1];
  for (u32 i = s + 1; i < e2; ++i) {
    u32 v = csr[i]; u32 j = i;
    while (j > s && csr[j - 1] > v) { csr[j] = csr[j - 1]; --j; }
    csr[j] = v;
  }
}

__global__ __launch_bounds__(256) void mm_xw1_k(const float* __restrict__ X,
                                                const float* __restrict__ W1,
                                                float* __restrict__ XW) {
  __shared__ float w[DIN * DH];
  for (int i = threadIdx.x; i < DIN * DH; i += 256) w[i] = W1[i];
  __syncthreads();
  int f = threadIdx.x & 31, r0 = threadIdx.x >> 5;
  int base = blockIdx.x * 32;
  for (int pass = 0; pass < 4; ++pass) {
    int r = base + r0 + pass * 8;
    const float4* xr = reinterpret_cast<const float4*>(X + (size_t)r * DIN);
    float acc = 0.0f;
    for (int k4 = 0; k4 < DIN / 4; ++k4) {
      float4 xv = xr[k4];
      int k = k4 * 4;
      acc = fmaf(xv.x, w[(k + 0) * DH + f], acc);
      acc = fmaf(xv.y, w[(k + 1) * DH + f], acc);
      acc = fmaf(xv.z, w[(k + 2) * DH + f], acc);
      acc = fmaf(xv.w, w[(k + 3) * DH + f], acc);
    }
    XW[(size_t)r * DH + f] = acc;
  }
}

__global__ void agg_h_k(const float* __restrict__ XW, const u32* __restrict__ off,
                        const u32* __restrict__ csr, const int* __restrict__ ei,
                        const float* __restrict__ dinv, const float* __restrict__ b1,
                        float* __restrict__ H) {
  int idx = blockIdx.x * blockDim.x + threadIdx.x;
  int n = idx >> 5, f = idx & 31;
  if (n >= NN) return;
  float dn = dinv[n];
  float acc = 0.0f;
  u32 s0 = off[n], s1 = off[n + 1];
  for (u32 p = s0; p < s1; ++p) {
    int e = (int)csr[p];
    int s = ei[e];
    acc += XW[s * DH + f] * (dinv[s] * dn);
  }
  acc += XW[n * DH + f] * (dn * dn);
  acc += b1[f];
  H[n * DH + f] = fmaxf(acc, 0.0f);
}

__global__ void mm_h_k(const float* __restrict__ H, const float* __restrict__ Wmu,
                       const float* __restrict__ Wk, float* __restrict__ HWmu,
                       float* __restrict__ HWk) {
  __shared__ float wm[DH * DL];
  __shared__ float wk[DH];
  for (int i = threadIdx.x; i < DH * DL; i += 256) wm[i] = Wmu[i];
  if (threadIdx.x < DH) wk[threadIdx.x] = Wk[threadIdx.x];
  __syncthreads();
  int f = threadIdx.x & 63, l = threadIdx.x >> 6;
  int n = blockIdx.x * 4 + l;
  const float* h = H + n * DH;
  float acc = 0.0f;
  for (int k = 0; k < DH; ++k) acc = fmaf(h[k], wm[k * DL + f], acc);
  HWmu[(size_t)n * DL + f] = acc;
  if (f == 0) {
    float a2 = 0.0f;
    for (int k = 0; k < DH; ++k) a2 = fmaf(h[k], wk[k], a2);
    HWk[n] = a2;
  }
}

__global__ void agg_mu_k(const float* __restrict__ HW, const u32* __restrict__ off,
                         const u32* __restrict__ csr, const int* __restrict__ ei,
                         const float* __restrict__ dinv, const float* __restrict__ bmu,
                         float* __restrict__ out) {
  int idx = blockIdx.x * blockDim.x + threadIdx.x;
  int n = idx >> 6, f = idx & 63;
  if (n >= NN) return;
  float dn = dinv[n], acc = 0.0f;
  for (u32 p = off[n]; p < off[n + 1]; ++p) {
    int e = (int)csr[p]; int s = ei[e];
    acc += HW[(size_t)s * DL + f] * (dinv[s] * dn);
  }
  acc += HW[(size_t)n * DL + f] * (dn * dn);
  out[(size_t)n * DL + f] = acc + bmu[f];
}

__global__ void agg_kap_k(const float* __restrict__ HWk, const u32* __restrict__ off,
                          const u32* __restrict__ csr, const int* __restrict__ ei,
                          const float* __restrict__ dinv, const float* __restrict__ bk,
                          float* __restrict__ kap, float* __restrict__ outKA) {
  int n = blockIdx.x * blockDim.x + threadIdx.x;
  if (n >= NN) return;
  float dn = dinv[n], acc = 0.0f;
  for (u32 p = off[n]; p < off[n + 1]; ++p) {
    int e = (int)csr[p]; int s = ei[e];
    acc += HWk[s] * (dinv[s] * dn);
  }
  acc += HWk[n] * (dn * dn);
  acc += bk[0];
  float sp = fmaxf(acc, 0.0f) + xla_log1pf(xla_expf(-fabsf(acc)));
  kap[n] = sp; outKA[n] = sp;
}

__global__ void norm_mus_k(const float* __restrict__ musraw, float* __restrict__ mus,
                           float* __restrict__ outMU) {
  int gid = blockIdx.x * blockDim.x + threadIdx.x;
  int n = gid >> 6, lane = threadIdx.x & 63;
  if (n >= NN) return;
  float v = musraw[(size_t)n * DL + lane];
  float nm = sqrtf(wave_sum(v * v)) + 1e-12f;
  float r = v / nm;
  mus[(size_t)n * DL + lane] = r;
  outMU[(size_t)n * DL + lane] = r;
}

// ---------------- sampling kernels ----------------

__global__ void build_keys_k(u32* __restrict__ ktab) {
  if (threadIdx.x != 0 || blockIdx.x != 0) return;
  Key root; root.a = 0u; root.b = 42u;
  Key kw = fold(root, 0u);
  Key kv = fold(root, 1u);
  ktab[192] = kv.a; ktab[193] = kv.b;
  for (int t = 0; t < 32; ++t) {
    Key kt = fold(kw, (u32)t);
    Key kb = fold(kt, 0u);
    Key ku = fold(kt, 1u);
    Key ka = fold(kb, 0u);
    Key kbb = fold(kb, 1u);
    ktab[6 * t + 0] = ka.a;  ktab[6 * t + 1] = ka.b;
    ktab[6 * t + 2] = kbb.a; ktab[6 * t + 3] = kbb.b;
    ktab[6 * t + 4] = ku.a;  ktab[6 * t + 5] = ku.b;
  }
}

__global__ void sample_w_k(const float* __restrict__ kap, const u32* __restrict__ ktab,
                           float* __restrict__ wv) {
  int n = blockIdx.x * blockDim.x + threadIdx.x;
  if (n >= NN) return;
  float kappa = kap[n];
  float kk = kappa * kappa;
  float s  = sqrtf(fmaf(4.0f, kk, 3969.0f));
  float bb = fmaf(-2.0f, kappa, s) / 63.0f;
  float aa = (fmaf(2.0f, kappa, 63.0f) + s) / 4.0f;
  float dd = (4.0f * aa) * bb / (1.0f + bb) - 261.01748776266657f;  // 63*log(63)
  float w = 0.0f;
  for (int t = 0; t < 32; ++t) {
    const u32* kt = ktab + 6 * t;
    Key ka; ka.a = kt[0]; ka.b = kt[1];
    Key kb; kb.a = kt[2]; kb.b = kt[3];
    Key ku; ku.a = kt[4]; ku.b = kt[5];
    Key sa = fold(ka, (u32)n);
    Key sb = fold(kb, (u32)n);
    float lga = loggamma31_5(sa);
    float lgb = loggamma31_5(sb);
    float mx = fmaxf(lga, lgb);
    float ea = xla_expf(lga - mx), eb = xla_expf(lgb - mx);
    float eps = ea / (ea + eb);
    float u = fmaxf(0.0f, u01_from_bits(pbits(ku, (u32)n)));
    float denom = fmaf(-(1.0f - bb), eps, 1.0f);
    w = fmaf(-(1.0f + bb), eps, 1.0f) / denom;
    float tt = (2.0f * aa) * bb / denom;
    float lt = xla_logf(tt);
    float margin = fmaf(63.0f, lt, -tt) + dd;
    if (margin >= xla_logf(u)) break;
  }
  wv[n] = w;
}

// z_k now emits bf16 Z (for the MFMA ZZt) — values computed in f32 as before.
__global__ void z_k(const float* __restrict__ mus, const float* __restrict__ wv,
                    const u32* __restrict__ ktab, __bf16* __restrict__ Zh) {
  int gid = blockIdx.x * blockDim.x + threadIdx.x;
  int n = gid >> 6, lane = threadIdx.x & 63;
  if (n >= NN) return;
  Key kv; kv.a = ktab[192]; kv.b = ktab[193];
  float vj = 0.0f;
  if (lane >= 1) {
    u32 idx = (u32)(n * 63 + (lane - 1));
    vj = normal_from_bits(pbits(kv, idx));
  }
  float vn = sqrtf(wave_sum(vj * vj));
  vj = vj / vn;
  float w = wv[n];
  float zj = (lane == 0) ? w : sqrtf(fmaxf(1.0f - w * w, 0.0f)) * vj;
  float mu = mus[(size_t)n * DL + lane];
  float uh = ((lane == 0) ? 1.0f : 0.0f) - mu;
  float un = sqrtf(wave_sum(uh * uh)) + 1e-8f;
  uh = uh / un;
  float dot = wave_sum(zj * uh);
  float zf = zj - 2.0f * dot * uh;
  Zh[(size_t)n * DL + lane] = (__bf16)zf;
}

// ---------------- ZZt via bf16 MFMA ----------------
// C = Z·Z^T is SYMMETRIC, so row/col-transpose ambiguity in fragment mapping
// cannot change the result; a wrong element mapping would blow absmax (caught).
// mfma_f32_16x16x32_bf16: lane l holds A[row=l&15][k=(l>>4)*8..+8] (8 bf16),
// B[k=(l>>4)*8..+8][col=l&15]; C: col=l&15, row=(l>>4)*4+reg (m89-verified).
__global__ __launch_bounds__(256) void zzt_k(const __bf16* __restrict__ Zh,
                                             float* __restrict__ out) {
  int wave = threadIdx.x >> 6;
  int lane = threadIdx.x & 63;
  int bi = blockIdx.y * 128 + (wave >> 1) * 64;
  int bj = blockIdx.x * 128 + (wave & 1) * 64;
  int r = lane & 15, kh = lane >> 4;         // kh = 0..3
  bf16x8 afr[4][2], bfr[4][2];
#pragma unroll
  for (int ig = 0; ig < 4; ++ig)
#pragma unroll
    for (int kk = 0; kk < 2; ++kk) {
      afr[ig][kk] = *reinterpret_cast<const bf16x8*>(
          Zh + (size_t)(bi + ig * 16 + r) * DL + kk * 32 + kh * 8);
      bfr[ig][kk] = *reinterpret_cast<const bf16x8*>(
          Zh + (size_t)(bj + ig * 16 + r) * DL + kk * 32 + kh * 8);
    }
  f32x4 acc[4][4];
#pragma unroll
  for (int ig = 0; ig < 4; ++ig)
#pragma unroll
    for (int jg = 0; jg < 4; ++jg) {
      acc[ig][jg] = (f32x4){0.0f, 0.0f, 0.0f, 0.0f};
      acc[ig][jg] = __builtin_amdgcn_mfma_f32_16x16x32_bf16(
          afr[ig][0], bfr[jg][0], acc[ig][jg], 0, 0, 0);
      acc[ig][jg] = __builtin_amdgcn_mfma_f32_16x16x32_bf16(
          afr[ig][1], bfr[jg][1], acc[ig][jg], 0, 0, 0);
    }
#pragma unroll
  for (int ig = 0; ig < 4; ++ig)
#pragma unroll
    for (int jg = 0; jg < 4; ++jg) {
      size_t rowbase = (size_t)(bi + ig * 16 + kh * 4);
#pragma unroll
      for (int rr = 0; rr < 4; ++rr) {
        out[(rowbase + rr) * NN + (bj + jg * 16 + r)] = acc[ig][jg][rr];
      }
    }
}

// ---------------- launch ----------------

extern "C" void kernel_launch(void* const* d_in, const int* in_sizes, int n_in,
                              void* d_out, int out_size, void* d_ws, size_t ws_size,
                              hipStream_t stream) {
  const float* X   = (const float*)d_in[0];
  const int*   ei  = (const int*)d_in[1];
  const float* W1  = (const float*)d_in[2];
  const float* b1  = (const float*)d_in[3];
  const float* Wmu = (const float*)d_in[4];
  const float* bmu = (const float*)d_in[5];
  const float* Wk  = (const float*)d_in[6];
  const float* bk  = (const float*)d_in[7];

  char* wp = (char*)d_ws;
  auto alloc = [&](size_t bytes) -> char* {
    char* p = wp; wp += (bytes + 255) & ~(size_t)255; return p;
  };
  u32* cnt    = (u32*)alloc((size_t)NN * 4);
  u32* fill   = (u32*)alloc((size_t)NN * 4);
  u32* off    = (u32*)alloc((size_t)(NN + 1) * 4);
  u32* csr    = (u32*)alloc((size_t)NE * 4);
  u32* ktab   = (u32*)alloc(256 * 4);
  float* dinv = (float*)alloc((size_t)NN * 4);
  float* XW1  = (float*)alloc((size_t)NN * DH * 4);
  float* H    = (float*)alloc((size_t)NN * DH * 4);
  float* HWmu = (float*)alloc((size_t)NN * DL * 4);
  float* HWk  = (float*)alloc((size_t)NN * 4);
  float* musr = (float*)alloc((size_t)NN * DL * 4);
  float* mus  = (float*)alloc((size_t)NN * DL * 4);
  float* kap  = (float*)alloc((size_t)NN * 4);
  float* wv   = (float*)alloc((size_t)NN * 4);
  __bf16* Zh  = (__bf16*)alloc((size_t)NN * DL * 2);

  float* outZZ = (float*)d_out;
  float* outMU = outZZ + (size_t)NN * NN;
  float* outKA = outMU + (size_t)NN * DL;

  hipMemsetAsync(cnt, 0, (size_t)NN * 4, stream);
  hipMemsetAsync(fill, 0, (size_t)NN * 4, stream);
  build_keys_k<<<1, 64, 0, stream>>>(ktab);
  count_k<<<NE / 256, 256, 0, stream>>>(ei, cnt);
  scan_k<<<1, 256, 0, stream>>>(cnt, off, dinv);
  fill_k<<<NE / 256, 256, 0, stream>>>(ei, off, fill, csr);
  sort_k<<<NN / 256, 256, 0, stream>>>(off, csr);
  mm_xw1_k<<<NN / 32, 256, 0, stream>>>(X, W1, XW1);
  agg_h_k<<<NN * DH / 256, 256, 0, stream>>>(XW1, off, csr, ei, dinv, b1, H);
  mm_h_k<<<NN / 4, 256, 0, stream>>>(H, Wmu, Wk, HWmu, HWk);
  agg_mu_k<<<NN * DL / 256, 256, 0, stream>>>(HWmu, off, csr, ei, dinv, bmu, musr);
  agg_kap_k<<<NN / 256, 256, 0, stream>>>(HWk, off, csr, ei, dinv, bk, kap, outKA);
  norm_mus_k<<<NN * DL / 256, 256, 0, stream>>>(musr, mus, outMU);
  sample_w_k<<<NN / 256, 256, 0, stream>>>(kap, ktab, wv);
  z_k<<<NN * DL / 256, 256, 0, stream>>>(mus, wv, ktab, Zh);
  dim3 g(64, 64);
  zzt_k<<<g, 256, 0, stream>>>(Zh, outZZ);
}

// Round 15
// 240.365 us; speedup vs baseline: 1.6537x; 1.1236x over previous
//
#include <hip/hip_runtime.h>
#include <hip/hip_bf16.h>

#pragma clang fp contract(off)

#define NN 8192
#define NE 131072
#define DIN 256
#define DH 32
#define DL 64

typedef unsigned int u32;
typedef __bf16 bf16x8 __attribute__((ext_vector_type(8)));
typedef float f32x4 __attribute__((ext_vector_type(4)));

struct Key { u32 a, b; };

__device__ __forceinline__ u32 rotl32(u32 x, int d) { return (x << d) | (x >> (32 - d)); }

// JAX threefry2x32: 20 rounds, 5 key injections.
__device__ __forceinline__ void tf2x32(u32 k0, u32 k1, u32& x0, u32& x1) {
  u32 k2 = k0 ^ k1 ^ 0x1BD11BDAu;
  x0 += k0; x1 += k1;
  x0 += x1; x1 = rotl32(x1, 13); x1 ^= x0;
  x0 += x1; x1 = rotl32(x1, 15); x1 ^= x0;
  x0 += x1; x1 = rotl32(x1, 26); x1 ^= x0;
  x0 += x1; x1 = rotl32(x1, 6);  x1 ^= x0;
  x0 += k1; x1 += k2 + 1u;
  x0 += x1; x1 = rotl32(x1, 17); x1 ^= x0;
  x0 += x1; x1 = rotl32(x1, 29); x1 ^= x0;
  x0 += x1; x1 = rotl32(x1, 16); x1 ^= x0;
  x0 += x1; x1 = rotl32(x1, 24); x1 ^= x0;
  x0 += k2; x1 += k0 + 2u;
  x0 += x1; x1 = rotl32(x1, 13); x1 ^= x0;
  x0 += x1; x1 = rotl32(x1, 15); x1 ^= x0;
  x0 += x1; x1 = rotl32(x1, 26); x1 ^= x0;
  x0 += x1; x1 = rotl32(x1, 6);  x1 ^= x0;
  x0 += k0; x1 += k1 + 3u;
  x0 += x1; x1 = rotl32(x1, 17); x1 ^= x0;
  x0 += x1; x1 = rotl32(x1, 29); x1 ^= x0;
  x0 += x1; x1 = rotl32(x1, 16); x1 ^= x0;
  x0 += x1; x1 = rotl32(x1, 24); x1 ^= x0;
  x0 += k1; x1 += k2 + 4u;
  x0 += x1; x1 = rotl32(x1, 13); x1 ^= x0;
  x0 += x1; x1 = rotl32(x1, 15); x1 ^= x0;
  x0 += x1; x1 = rotl32(x1, 26); x1 ^= x0;
  x0 += x1; x1 = rotl32(x1, 6);  x1 ^= x0;
  x0 += k2; x1 += k0 + 5u;
}

// jax_threefry_partitionable: split(key,n)[i] == fold_in(key,i) == block (0,i).
__device__ __forceinline__ Key fold(Key k, u32 i) {
  u32 x0 = 0u, x1 = i; tf2x32(k.a, k.b, x0, x1);
  Key r; r.a = x0; r.b = x1; return r;
}
__device__ __forceinline__ u32 pbits(Key k, u32 i) {
  u32 x0 = 0u, x1 = i; tf2x32(k.a, k.b, x0, x1);
  return x0 ^ x1;
}

// ---- XLA CPU transcendentals (Cephes, FMA'd) ----

__device__ __forceinline__ float xla_logf(float x) {
  if (x == 0.0f) return -__builtin_huge_valf();
  u32 bits = __float_as_uint(x);
  float ef = (float)((int)(bits >> 23) - 126);
  float m = __uint_as_float((bits & 0x007fffffu) | 0x3f000000u);
  if (m < 0.707106781186547524f) { ef = ef - 1.0f; m = m + m; }
  m = m - 1.0f;
  float z = m * m;
  float y = 7.0376836292e-2f;
  y = fmaf(y, m, -1.1514610310e-1f);
  y = fmaf(y, m, 1.1676998740e-1f);
  y = fmaf(y, m, -1.2420140846e-1f);
  y = fmaf(y, m, 1.4249322787e-1f);
  y = fmaf(y, m, -1.6668057665e-1f);
  y = fmaf(y, m, 2.0000714765e-1f);
  y = fmaf(y, m, -2.4999993993e-1f);
  y = fmaf(y, m, 3.3333331174e-1f);
  y = y * m;
  y = y * z;
  y = fmaf(ef, -2.12194440e-4f, y);
  y = fmaf(-0.5f, z, y);
  float r = m + y;
  r = fmaf(ef, 0.693359375f, r);
  return r;
}

__device__ __forceinline__ float xla_expf(float x) {
  x = fminf(x, 88.3762626647950f);
  x = fmaxf(x, -88.3762626647949f);
  float fx = fmaf(x, 1.44269504088896341f, 0.5f);
  fx = floorf(fx);
  x = fmaf(-fx, 0.693359375f, x);
  x = fmaf(fx, 2.12194440e-4f, x);
  float z = x * x;
  float y = 1.9875691500e-4f;
  y = fmaf(y, x, 1.3981999507e-3f);
  y = fmaf(y, x, 8.3334519073e-3f);
  y = fmaf(y, x, 4.1665795894e-2f);
  y = fmaf(y, x, 1.6666665459e-1f);
  y = fmaf(y, x, 5.0000001201e-1f);
  y = fmaf(y, z, x);
  y = y + 1.0f;
  int n = (int)fx;
  float p2n = __uint_as_float((u32)(n + 127) << 23);
  return y * p2n;
}

__device__ __forceinline__ float xla_log1pf(float x) {
  float u = x + 1.0f;
  if (u == 1.0f) return x;
  return xla_logf(u) * (x / (u - 1.0f));
}

__device__ __forceinline__ float u01_from_bits(u32 b) {
  return __uint_as_float((b >> 9) | 0x3f800000u) - 1.0f;
}
__device__ __forceinline__ float jax_uniform_scalar(Key k) {
  float f = u01_from_bits(pbits(k, 0u));
  return fmaxf(0.0f, f);
}

__device__ __forceinline__ float erfinv_f32(float x) {
  float w = -xla_log1pf(-(x * x));
  float p;
  if (w < 5.0f) {
    w = w - 2.5f;
    p = 2.81022636e-08f;
    p = fmaf(p, w, 3.43273939e-07f);
    p = fmaf(p, w, -3.5233877e-06f);
    p = fmaf(p, w, -4.39150654e-06f);
    p = fmaf(p, w, 0.00021858087f);
    p = fmaf(p, w, -0.00125372503f);
    p = fmaf(p, w, -0.00417768164f);
    p = fmaf(p, w, 0.246640727f);
    p = fmaf(p, w, 1.50140941f);
  } else {
    w = sqrtf(w) - 3.0f;
    p = -0.000200214257f;
    p = fmaf(p, w, 0.000100950558f);
    p = fmaf(p, w, 0.00134934322f);
    p = fmaf(p, w, -0.00367342844f);
    p = fmaf(p, w, 0.00573950773f);
    p = fmaf(p, w, -0.0076224613f);
    p = fmaf(p, w, 0.00943887047f);
    p = fmaf(p, w, 1.00167406f);
    p = fmaf(p, w, 2.83297682f);
  }
  return p * x;
}

__device__ __forceinline__ float normal_from_bits(u32 b) {
  float f = u01_from_bits(b);
  const float lo = -0.99999994f;
  float u = fmaxf(lo, fmaf(f, 2.0f, lo));
  return 1.4142135623730951f * erfinv_f32(u);
}

// jax _gamma_one, alpha=31.5, log_space=True — f32. MT c = 1/sqrt(9d).
__device__ float loggamma31_5(Key k) {
  const float dd = 31.5f - (1.0f / 3.0f);
  const float cc = 1.0f / sqrtf(9.0f * dd);
  Key key = fold(k, 0u);
  float X = 0.0f, V = 1.0f, U = 2.0f;
  for (int it = 0; it < 64; ++it) {
    bool c1 = U >= fmaf(-0.0331f, X * X, 1.0f);
    bool c2 = xla_logf(U) >= fmaf(dd, (1.0f - V) + xla_logf(V), X * 0.5f);
    if (!(c1 && c2)) break;
    Key xk = fold(key, 1u);
    Key Uk = fold(key, 2u);
    key = fold(key, 0u);
    float x = 0.0f, v = -1.0f;
    for (int j = 0; j < 32 && v <= 0.0f; ++j) {
      Key sk = fold(xk, 1u);
      xk = fold(xk, 0u);
      x = normal_from_bits(pbits(sk, 0u));
      v = fmaf(x, cc, 1.0f);
    }
    X = x * x; V = (v * v) * v;
    U = jax_uniform_scalar(Uk);
  }
  return xla_logf(V) + xla_logf(dd);
}

__device__ __forceinline__ float wave_sum(float v) {
  for (int d = 1; d < 64; d <<= 1) v += __shfl_xor(v, d, 64);
  return v;
}

// ---------------- graph build ----------------

__global__ void count_k(const int* __restrict__ ei, u32* __restrict__ cnt) {
  int e = blockIdx.x * blockDim.x + threadIdx.x;
  if (e < NE) atomicAdd(&cnt[ei[NE + e]], 1u);
}

__global__ void scan_k(const u32* __restrict__ cnt, u32* __restrict__ off, float* __restrict__ dinv) {
  __shared__ u32 part[256];
  int t = threadIdx.x;
  int base = t * 32;
  u32 s = 0;
  for (int i = 0; i < 32; ++i) s += cnt[base + i];
  part[t] = s;
  __syncthreads();
  if (t == 0) {
    u32 acc = 0;
    for (int i = 0; i < 256; ++i) { u32 v = part[i]; part[i] = acc; acc += v; }
  }
  __syncthreads();
  u32 acc = part[t];
  for (int i = 0; i < 32; ++i) {
    off[base + i] = acc;
    u32 c = cnt[base + i];
    acc += c;
    dinv[base + i] = 1.0f / sqrtf((float)(c + 1u));
  }
  if (t == 255) off[NN] = acc;
}

__global__ void fill_k(const int* __restrict__ ei, const u32* __restrict__ off,
                       u32* __restrict__ fl, u32* __restrict__ csr) {
  int e = blockIdx.x * blockDim.x + threadIdx.x;
  if (e < NE) {
    int d = ei[NE + e];
    u32 p = off[d] + atomicAdd(&fl[d], 1u);
    csr[p] = (u32)e;
  }
}

__global__ void sort_k(const u32* __restrict__ off, u32* __restrict__ csr) {
  int n = blockIdx.x * blockDim.x + threadIdx.x;
  if (n >= NN) return;
  u32 s = off[n], e2 = off[n + 1];
  for (u32 i = s + 1; i < e2; ++i) {
    u32 v = csr[i]; u32 j = i;
    while (j > s && csr[j - 1] > v) { csr[j] = csr[j - 1]; --j; }
    csr[j] = v;
  }
}

// ---------------- GCN ----------------

__global__ __launch_bounds__(256) void mm_xw1_k(const float* __restrict__ X,
                                                const float* __restrict__ W1,
                                                float* __restrict__ XW) {
  __shared__ float w[DIN * DH];
  for (int i = threadIdx.x; i < DIN * DH; i += 256) w[i] = W1[i];
  __syncthreads();
  int f = threadIdx.x & 31, r0 = threadIdx.x >> 5;
  int base = blockIdx.x * 32;
  for (int pass = 0; pass < 4; ++pass) {
    int r = base + r0 + pass * 8;
    const float4* xr = reinterpret_cast<const float4*>(X + (size_t)r * DIN);
    float acc = 0.0f;
    for (int k4 = 0; k4 < DIN / 4; ++k4) {
      float4 xv = xr[k4];
      int k = k4 * 4;
      acc = fmaf(xv.x, w[(k + 0) * DH + f], acc);
      acc = fmaf(xv.y, w[(k + 1) * DH + f], acc);
      acc = fmaf(xv.z, w[(k + 2) * DH + f], acc);
      acc = fmaf(xv.w, w[(k + 3) * DH + f], acc);
    }
    XW[(size_t)r * DH + f] = acc;
  }
}

// Fused agg_h + mm_h: H computed exactly as before (same per-thread fmaf
// chain), passed through LDS (bit-identical f32), then the H@Wmu / H@Wk
// chains run with identical k-ascending fmaf order.
__global__ __launch_bounds__(256) void agg_h_mm_k(const float* __restrict__ XW,
                                                  const u32* __restrict__ off,
                                                  const u32* __restrict__ csr,
                                                  const int* __restrict__ ei,
                                                  const float* __restrict__ dinv,
                                                  const float* __restrict__ b1,
                                                  const float* __restrict__ Wmu,
                                                  const float* __restrict__ Wk,
                                                  float* __restrict__ HWmu,
                                                  float* __restrict__ HWk) {
  __shared__ float Hs[8][DH];
  __shared__ float wm[DH * DL];
  __shared__ float wk[DH];
  for (int i = threadIdx.x; i < DH * DL; i += 256) wm[i] = Wmu[i];
  if (threadIdx.x < DH) wk[threadIdx.x] = Wk[threadIdx.x];
  // ---- agg_h part: 8 nodes/block, 32 features/node ----
  int nl = threadIdx.x >> 5, f = threadIdx.x & 31;
  int n = blockIdx.x * 8 + nl;
  {
    float dn = dinv[n];
    float acc = 0.0f;
    u32 s0 = off[n], s1 = off[n + 1];
    for (u32 p = s0; p < s1; ++p) {
      int e = (int)csr[p];
      int s = ei[e];
      acc += XW[(size_t)s * DH + f] * (dinv[s] * dn);
    }
    acc += XW[(size_t)n * DH + f] * (dn * dn);
    acc += b1[f];
    Hs[nl][f] = fmaxf(acc, 0.0f);
  }
  __syncthreads();
  // ---- mm_h part: 8 nodes x (64 mu + 1 kap) ----
  int f2 = threadIdx.x & 63, l = threadIdx.x >> 6;   // l = 0..3
#pragma unroll
  for (int rep = 0; rep < 2; ++rep) {
    int nl2 = l + rep * 4;
    int n2 = blockIdx.x * 8 + nl2;
    const float* h = Hs[nl2];
    float acc = 0.0f;
    for (int k = 0; k < DH; ++k) acc = fmaf(h[k], wm[k * DL + f2], acc);
    HWmu[(size_t)n2 * DL + f2] = acc;
    if (f2 == 0) {
      float a2 = 0.0f;
      for (int k = 0; k < DH; ++k) a2 = fmaf(h[k], wk[k], a2);
      HWk[n2] = a2;
    }
  }
}

// Fused agg_mu (blocks 0..2047) + agg_kap (blocks 2048..2079); bodies verbatim.
__global__ void agg_mu_kap_k(const float* __restrict__ HW, const float* __restrict__ HWk,
                             const u32* __restrict__ off, const u32* __restrict__ csr,
                             const int* __restrict__ ei, const float* __restrict__ dinv,
                             const float* __restrict__ bmu, const float* __restrict__ bk,
                             float* __restrict__ musr, float* __restrict__ kap,
                             float* __restrict__ outKA) {
  int bid = blockIdx.x;
  if (bid < 2048) {
    int idx = bid * 256 + threadIdx.x;
    int n = idx >> 6, f = idx & 63;
    float dn = dinv[n], acc = 0.0f;
    for (u32 p = off[n]; p < off[n + 1]; ++p) {
      int e = (int)csr[p]; int s = ei[e];
      acc += HW[(size_t)s * DL + f] * (dinv[s] * dn);
    }
    acc += HW[(size_t)n * DL + f] * (dn * dn);
    musr[(size_t)n * DL + f] = acc + bmu[f];
  } else {
    int n = (bid - 2048) * 256 + threadIdx.x;
    if (n >= NN) return;
    float dn = dinv[n], acc = 0.0f;
    for (u32 p = off[n]; p < off[n + 1]; ++p) {
      int e = (int)csr[p]; int s = ei[e];
      acc += HWk[s] * (dinv[s] * dn);
    }
    acc += HWk[n] * (dn * dn);
    acc += bk[0];
    float sp = fmaxf(acc, 0.0f) + xla_log1pf(xla_expf(-fabsf(acc)));
    kap[n] = sp; outKA[n] = sp;
  }
}

// Fused norm_mus (blocks 0..2047) + sample_w (blocks 2048..2079).
// sample_w derives its per-iteration keys inline (pure integer, identical
// values to the old ktab path).
__global__ void norm_sample_k(const float* __restrict__ musraw, float* __restrict__ mus,
                              float* __restrict__ outMU, const float* __restrict__ kap,
                              float* __restrict__ wv) {
  int bid = blockIdx.x;
  if (bid < 2048) {
    int gid = bid * 256 + threadIdx.x;
    int n = gid >> 6, lane = threadIdx.x & 63;
    float v = musraw[(size_t)n * DL + lane];
    float nm = sqrtf(wave_sum(v * v)) + 1e-12f;
    float r = v / nm;
    mus[(size_t)n * DL + lane] = r;
    outMU[(size_t)n * DL + lane] = r;
  } else {
    int n = (bid - 2048) * 256 + threadIdx.x;
    if (n >= NN) return;
    Key root; root.a = 0u; root.b = 42u;
    Key kw = fold(root, 0u);              // kw, kv = split(key)
    float kappa = kap[n];
    float kk = kappa * kappa;
    float s  = sqrtf(fmaf(4.0f, kk, 3969.0f));
    float bb = fmaf(-2.0f, kappa, s) / 63.0f;
    float aa = (fmaf(2.0f, kappa, 63.0f) + s) / 4.0f;
    float dd = (4.0f * aa) * bb / (1.0f + bb) - 261.01748776266657f;  // 63*log63
    float w = 0.0f;
    for (int t = 0; t < 32; ++t) {
      Key kt = fold(kw, (u32)t);          // split(kw, 32)[t]
      Key kb = fold(kt, 0u);              // kb, ku = split(k)
      Key ku = fold(kt, 1u);
      Key ka = fold(kb, 0u);              // key_a, key_b = split(kb)
      Key kbb = fold(kb, 1u);
      Key sa = fold(ka, (u32)n);
      Key sb = fold(kbb, (u32)n);
      float lga = loggamma31_5(sa);
      float lgb = loggamma31_5(sb);
      float mx = fmaxf(lga, lgb);
      float ea = xla_expf(lga - mx), eb = xla_expf(lgb - mx);
      float eps = ea / (ea + eb);
      float u = fmaxf(0.0f, u01_from_bits(pbits(ku, (u32)n)));
      float denom = fmaf(-(1.0f - bb), eps, 1.0f);
      w = fmaf(-(1.0f + bb), eps, 1.0f) / denom;
      float tt = (2.0f * aa) * bb / denom;
      float lt = xla_logf(tt);
      float margin = fmaf(63.0f, lt, -tt) + dd;
      if (margin >= xla_logf(u)) break;
    }
    wv[n] = w;
  }
}

// z_k: kv derived inline; emits bf16 Z for the MFMA ZZt.
__global__ void z_k(const float* __restrict__ mus, const float* __restrict__ wv,
                    __bf16* __restrict__ Zh) {
  int gid = blockIdx.x * blockDim.x + threadIdx.x;
  int n = gid >> 6, lane = threadIdx.x & 63;
  if (n >= NN) return;
  Key root; root.a = 0u; root.b = 42u;
  Key kv = fold(root, 1u);
  float vj = 0.0f;
  if (lane >= 1) {
    u32 idx = (u32)(n * 63 + (lane - 1));
    vj = normal_from_bits(pbits(kv, idx));
  }
  float vn = sqrtf(wave_sum(vj * vj));
  vj = vj / vn;
  float w = wv[n];
  float zj = (lane == 0) ? w : sqrtf(fmaxf(1.0f - w * w, 0.0f)) * vj;
  float mu = mus[(size_t)n * DL + lane];
  float uh = ((lane == 0) ? 1.0f : 0.0f) - mu;
  float un = sqrtf(wave_sum(uh * uh)) + 1e-8f;
  uh = uh / un;
  float dot = wave_sum(zj * uh);
  float zf = zj - 2.0f * dot * uh;
  Zh[(size_t)n * DL + lane] = (__bf16)zf;
}

// ---------------- ZZt via bf16 MFMA, transposed float4 stores ----------------
// acc[ig][jg] reg rr at lane (r,kh) holds C[bi+ig*16+kh*4+rr][bj+jg*16+r].
// out[bj+col][bi+row] equals the SAME dot product (Z_row . Z_col), so we
// store each reg-quad as one float4 at the transposed location: 16 float4
// stores/thread instead of 64 scalar stores; lanes kh=0..3 merge into
// contiguous 64B runs per output row.
__global__ __launch_bounds__(256) void zzt_k(const __bf16* __restrict__ Zh,
                                             float* __restrict__ out) {
  int wave = threadIdx.x >> 6;
  int lane = threadIdx.x & 63;
  int bi = blockIdx.y * 128 + (wave >> 1) * 64;
  int bj = blockIdx.x * 128 + (wave & 1) * 64;
  int r = lane & 15, kh = lane >> 4;
  bf16x8 afr[4][2], bfr[4][2];
#pragma unroll
  for (int ig = 0; ig < 4; ++ig)
#pragma unroll
    for (int kk = 0; kk < 2; ++kk) {
      afr[ig][kk] = *reinterpret_cast<const bf16x8*>(
          Zh + (size_t)(bi + ig * 16 + r) * DL + kk * 32 + kh * 8);
      bfr[ig][kk] = *reinterpret_cast<const bf16x8*>(
          Zh + (size_t)(bj + ig * 16 + r) * DL + kk * 32 + kh * 8);
    }
  f32x4 acc[4][4];
#pragma unroll
  for (int ig = 0; ig < 4; ++ig)
#pragma unroll
    for (int jg = 0; jg < 4; ++jg) {
      acc[ig][jg] = (f32x4){0.0f, 0.0f, 0.0f, 0.0f};
      acc[ig][jg] = __builtin_amdgcn_mfma_f32_16x16x32_bf16(
          afr[ig][0], bfr[jg][0], acc[ig][jg], 0, 0, 0);
      acc[ig][jg] = __builtin_amdgcn_mfma_f32_16x16x32_bf16(
          afr[ig][1], bfr[jg][1], acc[ig][jg], 0, 0, 0);
    }
#pragma unroll
  for (int ig = 0; ig < 4; ++ig)
#pragma unroll
    for (int jg = 0; jg < 4; ++jg) {
      size_t row = (size_t)(bj + jg * 16 + r);
      float4 v = make_float4(acc[ig][jg][0], acc[ig][jg][1],
                             acc[ig][jg][2], acc[ig][jg][3]);
      *reinterpret_cast<float4*>(&out[row * NN + (bi + ig * 16 + kh * 4)]) = v;
    }
}

// ---------------- launch ----------------

extern "C" void kernel_launch(void* const* d_in, const int* in_sizes, int n_in,
                              void* d_out, int out_size, void* d_ws, size_t ws_size,
                              hipStream_t stream) {
  const float* X   = (const float*)d_in[0];
  const int*   ei  = (const int*)d_in[1];
  const float* W1  = (const float*)d_in[2];
  const float* b1  = (const float*)d_in[3];
  const float* Wmu = (const float*)d_in[4];
  const float* bmu = (const float*)d_in[5];
  const float* Wk  = (const float*)d_in[6];
  const float* bk  = (const float*)d_in[7];

  char* wp = (char*)d_ws;
  auto alloc = [&](size_t bytes) -> char* {
    char* p = wp; wp += (bytes + 255) & ~(size_t)255; return p;
  };
  u32* cnt    = (u32*)alloc((size_t)NN * 4);   // cnt+fill adjacent: one memset
  u32* fill   = (u32*)alloc((size_t)NN * 4);
  u32* off    = (u32*)alloc((size_t)(NN + 1) * 4);
  u32* csr    = (u32*)alloc((size_t)NE * 4);
  float* dinv = (float*)alloc((size_t)NN * 4);
  float* XW1  = (float*)alloc((size_t)NN * DH * 4);
  float* HWmu = (float*)alloc((size_t)NN * DL * 4);
  float* HWk  = (float*)alloc((size_t)NN * 4);
  float* musr = (float*)alloc((size_t)NN * DL * 4);
  float* mus  = (float*)alloc((size_t)NN * DL * 4);
  float* kap  = (float*)alloc((size_t)NN * 4);
  float* wv   = (float*)alloc((size_t)NN * 4);
  __bf16* Zh  = (__bf16*)alloc((size_t)NN * DL * 2);

  float* outZZ = (float*)d_out;
  float* outMU = outZZ + (size_t)NN * NN;
  float* outKA = outMU + (size_t)NN * DL;

  hipMemsetAsync(cnt, 0, (size_t)NN * 8, stream);   // zeroes cnt AND fill
  count_k<<<NE / 256, 256, 0, stream>>>(ei, cnt);
  scan_k<<<1, 256, 0, stream>>>(cnt, off, dinv);
  fill_k<<<NE / 256, 256, 0, stream>>>(ei, off, fill, csr);
  sort_k<<<NN / 256, 256, 0, stream>>>(off, csr);
  mm_xw1_k<<<NN / 32, 256, 0, stream>>>(X, W1, XW1);
  agg_h_mm_k<<<NN / 8, 256, 0, stream>>>(XW1, off, csr, ei, dinv, b1, Wmu, Wk,
                                         HWmu, HWk);
  agg_mu_kap_k<<<2048 + NN / 256, 256, 0, stream>>>(HWmu, HWk, off, csr, ei, dinv,
                                                    bmu, bk, musr, kap, outKA);
  norm_sample_k<<<2048 + NN / 256, 256, 0, stream>>>(musr, mus, outMU, kap, wv);
  z_k<<<NN * DL / 256, 256, 0, stream>>>(mus, wv, Zh);
  dim3 g(64, 64);
  zzt_k<<<g, 256, 0, stream>>>(Zh, outZZ);
}

// Round 16
// 236.849 us; speedup vs baseline: 1.6782x; 1.0148x over previous
//
#include <hip/hip_runtime.h>
#include <hip/hip_bf16.h>

#pragma clang fp contract(off)

#define NN 8192
#define NE 131072
#define DIN 256
#define DH 32
#define DL 64

typedef unsigned int u32;
typedef __bf16 bf16x8 __attribute__((ext_vector_type(8)));
typedef float f32x4 __attribute__((ext_vector_type(4)));

struct Key { u32 a, b; };

__device__ __forceinline__ u32 rotl32(u32 x, int d) { return (x << d) | (x >> (32 - d)); }

// JAX threefry2x32: 20 rounds, 5 key injections.
__device__ __forceinline__ void tf2x32(u32 k0, u32 k1, u32& x0, u32& x1) {
  u32 k2 = k0 ^ k1 ^ 0x1BD11BDAu;
  x0 += k0; x1 += k1;
  x0 += x1; x1 = rotl32(x1, 13); x1 ^= x0;
  x0 += x1; x1 = rotl32(x1, 15); x1 ^= x0;
  x0 += x1; x1 = rotl32(x1, 26); x1 ^= x0;
  x0 += x1; x1 = rotl32(x1, 6);  x1 ^= x0;
  x0 += k1; x1 += k2 + 1u;
  x0 += x1; x1 = rotl32(x1, 17); x1 ^= x0;
  x0 += x1; x1 = rotl32(x1, 29); x1 ^= x0;
  x0 += x1; x1 = rotl32(x1, 16); x1 ^= x0;
  x0 += x1; x1 = rotl32(x1, 24); x1 ^= x0;
  x0 += k2; x1 += k0 + 2u;
  x0 += x1; x1 = rotl32(x1, 13); x1 ^= x0;
  x0 += x1; x1 = rotl32(x1, 15); x1 ^= x0;
  x0 += x1; x1 = rotl32(x1, 26); x1 ^= x0;
  x0 += x1; x1 = rotl32(x1, 6);  x1 ^= x0;
  x0 += k0; x1 += k1 + 3u;
  x0 += x1; x1 = rotl32(x1, 17); x1 ^= x0;
  x0 += x1; x1 = rotl32(x1, 29); x1 ^= x0;
  x0 += x1; x1 = rotl32(x1, 16); x1 ^= x0;
  x0 += x1; x1 = rotl32(x1, 24); x1 ^= x0;
  x0 += k1; x1 += k2 + 4u;
  x0 += x1; x1 = rotl32(x1, 13); x1 ^= x0;
  x0 += x1; x1 = rotl32(x1, 15); x1 ^= x0;
  x0 += x1; x1 = rotl32(x1, 26); x1 ^= x0;
  x0 += x1; x1 = rotl32(x1, 6);  x1 ^= x0;
  x0 += k2; x1 += k0 + 5u;
}

// jax_threefry_partitionable: split(key,n)[i] == fold_in(key,i) == block (0,i).
__device__ __forceinline__ Key fold(Key k, u32 i) {
  u32 x0 = 0u, x1 = i; tf2x32(k.a, k.b, x0, x1);
  Key r; r.a = x0; r.b = x1; return r;
}
__device__ __forceinline__ u32 pbits(Key k, u32 i) {
  u32 x0 = 0u, x1 = i; tf2x32(k.a, k.b, x0, x1);
  return x0 ^ x1;
}

// ---- XLA CPU transcendentals (Cephes, FMA'd) ----

__device__ __forceinline__ float xla_logf(float x) {
  if (x == 0.0f) return -__builtin_huge_valf();
  u32 bits = __float_as_uint(x);
  float ef = (float)((int)(bits >> 23) - 126);
  float m = __uint_as_float((bits & 0x007fffffu) | 0x3f000000u);
  if (m < 0.707106781186547524f) { ef = ef - 1.0f; m = m + m; }
  m = m - 1.0f;
  float z = m * m;
  float y = 7.0376836292e-2f;
  y = fmaf(y, m, -1.1514610310e-1f);
  y = fmaf(y, m, 1.1676998740e-1f);
  y = fmaf(y, m, -1.2420140846e-1f);
  y = fmaf(y, m, 1.4249322787e-1f);
  y = fmaf(y, m, -1.6668057665e-1f);
  y = fmaf(y, m, 2.0000714765e-1f);
  y = fmaf(y, m, -2.4999993993e-1f);
  y = fmaf(y, m, 3.3333331174e-1f);
  y = y * m;
  y = y * z;
  y = fmaf(ef, -2.12194440e-4f, y);
  y = fmaf(-0.5f, z, y);
  float r = m + y;
  r = fmaf(ef, 0.693359375f, r);
  return r;
}

__device__ __forceinline__ float xla_expf(float x) {
  x = fminf(x, 88.3762626647950f);
  x = fmaxf(x, -88.3762626647949f);
  float fx = fmaf(x, 1.44269504088896341f, 0.5f);
  fx = floorf(fx);
  x = fmaf(-fx, 0.693359375f, x);
  x = fmaf(fx, 2.12194440e-4f, x);
  float z = x * x;
  float y = 1.9875691500e-4f;
  y = fmaf(y, x, 1.3981999507e-3f);
  y = fmaf(y, x, 8.3334519073e-3f);
  y = fmaf(y, x, 4.1665795894e-2f);
  y = fmaf(y, x, 1.6666665459e-1f);
  y = fmaf(y, x, 5.0000001201e-1f);
  y = fmaf(y, z, x);
  y = y + 1.0f;
  int n = (int)fx;
  float p2n = __uint_as_float((u32)(n + 127) << 23);
  return y * p2n;
}

__device__ __forceinline__ float xla_log1pf(float x) {
  float u = x + 1.0f;
  if (u == 1.0f) return x;
  return xla_logf(u) * (x / (u - 1.0f));
}

__device__ __forceinline__ float u01_from_bits(u32 b) {
  return __uint_as_float((b >> 9) | 0x3f800000u) - 1.0f;
}
__device__ __forceinline__ float jax_uniform_scalar(Key k) {
  float f = u01_from_bits(pbits(k, 0u));
  return fmaxf(0.0f, f);
}

__device__ __forceinline__ float erfinv_f32(float x) {
  float w = -xla_log1pf(-(x * x));
  float p;
  if (w < 5.0f) {
    w = w - 2.5f;
    p = 2.81022636e-08f;
    p = fmaf(p, w, 3.43273939e-07f);
    p = fmaf(p, w, -3.5233877e-06f);
    p = fmaf(p, w, -4.39150654e-06f);
    p = fmaf(p, w, 0.00021858087f);
    p = fmaf(p, w, -0.00125372503f);
    p = fmaf(p, w, -0.00417768164f);
    p = fmaf(p, w, 0.246640727f);
    p = fmaf(p, w, 1.50140941f);
  } else {
    w = sqrtf(w) - 3.0f;
    p = -0.000200214257f;
    p = fmaf(p, w, 0.000100950558f);
    p = fmaf(p, w, 0.00134934322f);
    p = fmaf(p, w, -0.00367342844f);
    p = fmaf(p, w, 0.00573950773f);
    p = fmaf(p, w, -0.0076224613f);
    p = fmaf(p, w, 0.00943887047f);
    p = fmaf(p, w, 1.00167406f);
    p = fmaf(p, w, 2.83297682f);
  }
  return p * x;
}

__device__ __forceinline__ float normal_from_bits(u32 b) {
  float f = u01_from_bits(b);
  const float lo = -0.99999994f;
  float u = fmaxf(lo, fmaf(f, 2.0f, lo));
  return 1.4142135623730951f * erfinv_f32(u);
}

// jax _gamma_one, alpha=31.5, log_space=True — f32. MT c = 1/sqrt(9d).
__device__ float loggamma31_5(Key k) {
  const float dd = 31.5f - (1.0f / 3.0f);
  const float cc = 1.0f / sqrtf(9.0f * dd);
  Key key = fold(k, 0u);
  float X = 0.0f, V = 1.0f, U = 2.0f;
  for (int it = 0; it < 64; ++it) {
    bool c1 = U >= fmaf(-0.0331f, X * X, 1.0f);
    bool c2 = xla_logf(U) >= fmaf(dd, (1.0f - V) + xla_logf(V), X * 0.5f);
    if (!(c1 && c2)) break;
    Key xk = fold(key, 1u);
    Key Uk = fold(key, 2u);
    key = fold(key, 0u);
    float x = 0.0f, v = -1.0f;
    for (int j = 0; j < 32 && v <= 0.0f; ++j) {
      Key sk = fold(xk, 1u);
      xk = fold(xk, 0u);
      x = normal_from_bits(pbits(sk, 0u));
      v = fmaf(x, cc, 1.0f);
    }
    X = x * x; V = (v * v) * v;
    U = jax_uniform_scalar(Uk);
  }
  return xla_logf(V) + xla_logf(dd);
}

__device__ __forceinline__ float wave_sum(float v) {
  for (int d = 1; d < 64; d <<= 1) v += __shfl_xor(v, d, 64);
  return v;
}

// ---------------- graph build ----------------

// Replaces in-graph hipMemsetAsync: rocclr fillBufferAligned measured at
// ~157 us PER CALL on graph replay (r14/r15 counters) regardless of size.
__global__ void zero_k(u32* __restrict__ cnt, u32* __restrict__ fl) {
  int i = blockIdx.x * blockDim.x + threadIdx.x;
  if (i < NN) { cnt[i] = 0u; fl[i] = 0u; }
}

__global__ void count_k(const int* __restrict__ ei, u32* __restrict__ cnt) {
  int e = blockIdx.x * blockDim.x + threadIdx.x;
  if (e < NE) atomicAdd(&cnt[ei[NE + e]], 1u);
}

__global__ void scan_k(const u32* __restrict__ cnt, u32* __restrict__ off, float* __restrict__ dinv) {
  __shared__ u32 part[256];
  int t = threadIdx.x;
  int base = t * 32;
  u32 s = 0;
  for (int i = 0; i < 32; ++i) s += cnt[base + i];
  part[t] = s;
  __syncthreads();
  if (t == 0) {
    u32 acc = 0;
    for (int i = 0; i < 256; ++i) { u32 v = part[i]; part[i] = acc; acc += v; }
  }
  __syncthreads();
  u32 acc = part[t];
  for (int i = 0; i < 32; ++i) {
    off[base + i] = acc;
    u32 c = cnt[base + i];
    acc += c;
    dinv[base + i] = 1.0f / sqrtf((float)(c + 1u));
  }
  if (t == 255) off[NN] = acc;
}

__global__ void fill_k(const int* __restrict__ ei, const u32* __restrict__ off,
                       u32* __restrict__ fl, u32* __restrict__ csr) {
  int e = blockIdx.x * blockDim.x + threadIdx.x;
  if (e < NE) {
    int d = ei[NE + e];
    u32 p = off[d] + atomicAdd(&fl[d], 1u);
    csr[p] = (u32)e;
  }
}

__global__ void sort_k(const u32* __restrict__ off, u32* __restrict__ csr) {
  int n = blockIdx.x * blockDim.x + threadIdx.x;
  if (n >= NN) return;
  u32 s = off[n], e2 = off[n + 1];
  for (u32 i = s + 1; i < e2; ++i) {
    u32 v = csr[i]; u32 j = i;
    while (j > s && csr[j - 1] > v) { csr[j] = csr[j - 1]; --j; }
    csr[j] = v;
  }
}

// ---------------- GCN ----------------

__global__ __launch_bounds__(256) void mm_xw1_k(const float* __restrict__ X,
                                                const float* __restrict__ W1,
                                                float* __restrict__ XW) {
  __shared__ float w[DIN * DH];
  for (int i = threadIdx.x; i < DIN * DH; i += 256) w[i] = W1[i];
  __syncthreads();
  int f = threadIdx.x & 31, r0 = threadIdx.x >> 5;
  int base = blockIdx.x * 32;
  for (int pass = 0; pass < 4; ++pass) {
    int r = base + r0 + pass * 8;
    const float4* xr = reinterpret_cast<const float4*>(X + (size_t)r * DIN);
    float acc = 0.0f;
    for (int k4 = 0; k4 < DIN / 4; ++k4) {
      float4 xv = xr[k4];
      int k = k4 * 4;
      acc = fmaf(xv.x, w[(k + 0) * DH + f], acc);
      acc = fmaf(xv.y, w[(k + 1) * DH + f], acc);
      acc = fmaf(xv.z, w[(k + 2) * DH + f], acc);
      acc = fmaf(xv.w, w[(k + 3) * DH + f], acc);
    }
    XW[(size_t)r * DH + f] = acc;
  }
}

// Fused agg_h + mm_h (H through LDS; bit-identical f32 chains).
__global__ __launch_bounds__(256) void agg_h_mm_k(const float* __restrict__ XW,
                                                  const u32* __restrict__ off,
                                                  const u32* __restrict__ csr,
                                                  const int* __restrict__ ei,
                                                  const float* __restrict__ dinv,
                                                  const float* __restrict__ b1,
                                                  const float* __restrict__ Wmu,
                                                  const float* __restrict__ Wk,
                                                  float* __restrict__ HWmu,
                                                  float* __restrict__ HWk) {
  __shared__ float Hs[8][DH];
  __shared__ float wm[DH * DL];
  __shared__ float wk[DH];
  for (int i = threadIdx.x; i < DH * DL; i += 256) wm[i] = Wmu[i];
  if (threadIdx.x < DH) wk[threadIdx.x] = Wk[threadIdx.x];
  int nl = threadIdx.x >> 5, f = threadIdx.x & 31;
  int n = blockIdx.x * 8 + nl;
  {
    float dn = dinv[n];
    float acc = 0.0f;
    u32 s0 = off[n], s1 = off[n + 1];
    for (u32 p = s0; p < s1; ++p) {
      int e = (int)csr[p];
      int s = ei[e];
      acc += XW[(size_t)s * DH + f] * (dinv[s] * dn);
    }
    acc += XW[(size_t)n * DH + f] * (dn * dn);
    acc += b1[f];
    Hs[nl][f] = fmaxf(acc, 0.0f);
  }
  __syncthreads();
  int f2 = threadIdx.x & 63, l = threadIdx.x >> 6;
#pragma unroll
  for (int rep = 0; rep < 2; ++rep) {
    int nl2 = l + rep * 4;
    int n2 = blockIdx.x * 8 + nl2;
    const float* h = Hs[nl2];
    float acc = 0.0f;
    for (int k = 0; k < DH; ++k) acc = fmaf(h[k], wm[k * DL + f2], acc);
    HWmu[(size_t)n2 * DL + f2] = acc;
    if (f2 == 0) {
      float a2 = 0.0f;
      for (int k = 0; k < DH; ++k) a2 = fmaf(h[k], wk[k], a2);
      HWk[n2] = a2;
    }
  }
}

// Fused agg_mu (blocks 0..2047) + agg_kap (blocks 2048..2079).
__global__ void agg_mu_kap_k(const float* __restrict__ HW, const float* __restrict__ HWk,
                             const u32* __restrict__ off, const u32* __restrict__ csr,
                             const int* __restrict__ ei, const float* __restrict__ dinv,
                             const float* __restrict__ bmu, const float* __restrict__ bk,
                             float* __restrict__ musr, float* __restrict__ kap,
                             float* __restrict__ outKA) {
  int bid = blockIdx.x;
  if (bid < 2048) {
    int idx = bid * 256 + threadIdx.x;
    int n = idx >> 6, f = idx & 63;
    float dn = dinv[n], acc = 0.0f;
    for (u32 p = off[n]; p < off[n + 1]; ++p) {
      int e = (int)csr[p]; int s = ei[e];
      acc += HW[(size_t)s * DL + f] * (dinv[s] * dn);
    }
    acc += HW[(size_t)n * DL + f] * (dn * dn);
    musr[(size_t)n * DL + f] = acc + bmu[f];
  } else {
    int n = (bid - 2048) * 256 + threadIdx.x;
    if (n >= NN) return;
    float dn = dinv[n], acc = 0.0f;
    for (u32 p = off[n]; p < off[n + 1]; ++p) {
      int e = (int)csr[p]; int s = ei[e];
      acc += HWk[s] * (dinv[s] * dn);
    }
    acc += HWk[n] * (dn * dn);
    acc += bk[0];
    float sp = fmaxf(acc, 0.0f) + xla_log1pf(xla_expf(-fabsf(acc)));
    kap[n] = sp; outKA[n] = sp;
  }
}

// Fused norm_mus (blocks 0..2047) + sample_w (blocks 2048..2079).
__global__ void norm_sample_k(const float* __restrict__ musraw, float* __restrict__ mus,
                              float* __restrict__ outMU, const float* __restrict__ kap,
                              float* __restrict__ wv) {
  int bid = blockIdx.x;
  if (bid < 2048) {
    int gid = bid * 256 + threadIdx.x;
    int n = gid >> 6, lane = threadIdx.x & 63;
    float v = musraw[(size_t)n * DL + lane];
    float nm = sqrtf(wave_sum(v * v)) + 1e-12f;
    float r = v / nm;
    mus[(size_t)n * DL + lane] = r;
    outMU[(size_t)n * DL + lane] = r;
  } else {
    int n = (bid - 2048) * 256 + threadIdx.x;
    if (n >= NN) return;
    Key root; root.a = 0u; root.b = 42u;
    Key kw = fold(root, 0u);
    float kappa = kap[n];
    float kk = kappa * kappa;
    float s  = sqrtf(fmaf(4.0f, kk, 3969.0f));
    float bb = fmaf(-2.0f, kappa, s) / 63.0f;
    float aa = (fmaf(2.0f, kappa, 63.0f) + s) / 4.0f;
    float dd = (4.0f * aa) * bb / (1.0f + bb) - 261.01748776266657f;
    float w = 0.0f;
    for (int t = 0; t < 32; ++t) {
      Key kt = fold(kw, (u32)t);
      Key kb = fold(kt, 0u);
      Key ku = fold(kt, 1u);
      Key ka = fold(kb, 0u);
      Key kbb = fold(kb, 1u);
      Key sa = fold(ka, (u32)n);
      Key sb = fold(kbb, (u32)n);
      float lga = loggamma31_5(sa);
      float lgb = loggamma31_5(sb);
      float mx = fmaxf(lga, lgb);
      float ea = xla_expf(lga - mx), eb = xla_expf(lgb - mx);
      float eps = ea / (ea + eb);
      float u = fmaxf(0.0f, u01_from_bits(pbits(ku, (u32)n)));
      float denom = fmaf(-(1.0f - bb), eps, 1.0f);
      w = fmaf(-(1.0f + bb), eps, 1.0f) / denom;
      float tt = (2.0f * aa) * bb / denom;
      float lt = xla_logf(tt);
      float margin = fmaf(63.0f, lt, -tt) + dd;
      if (margin >= xla_logf(u)) break;
    }
    wv[n] = w;
  }
}

// z_k: kv derived inline; emits bf16 Z.
__global__ void z_k(const float* __restrict__ mus, const float* __restrict__ wv,
                    __bf16* __restrict__ Zh) {
  int gid = blockIdx.x * blockDim.x + threadIdx.x;
  int n = gid >> 6, lane = threadIdx.x & 63;
  if (n >= NN) return;
  Key root; root.a = 0u; root.b = 42u;
  Key kv = fold(root, 1u);
  float vj = 0.0f;
  if (lane >= 1) {
    u32 idx = (u32)(n * 63 + (lane - 1));
    vj = normal_from_bits(pbits(kv, idx));
  }
  float vn = sqrtf(wave_sum(vj * vj));
  vj = vj / vn;
  float w = wv[n];
  float zj = (lane == 0) ? w : sqrtf(fmaxf(1.0f - w * w, 0.0f)) * vj;
  float mu = mus[(size_t)n * DL + lane];
  float uh = ((lane == 0) ? 1.0f : 0.0f) - mu;
  float un = sqrtf(wave_sum(uh * uh)) + 1e-8f;
  uh = uh / un;
  float dot = wave_sum(zj * uh);
  float zf = zj - 2.0f * dot * uh;
  Zh[(size_t)n * DL + lane] = (__bf16)zf;
}

// ---------------- ZZt via bf16 MFMA, transposed float4 stores ----------------
__global__ __launch_bounds__(256) void zzt_k(const __bf16* __restrict__ Zh,
                                             float* __restrict__ out) {
  int wave = threadIdx.x >> 6;
  int lane = threadIdx.x & 63;
  int bi = blockIdx.y * 128 + (wave >> 1) * 64;
  int bj = blockIdx.x * 128 + (wave & 1) * 64;
  int r = lane & 15, kh = lane >> 4;
  bf16x8 afr[4][2], bfr[4][2];
#pragma unroll
  for (int ig = 0; ig < 4; ++ig)
#pragma unroll
    for (int kk = 0; kk < 2; ++kk) {
      afr[ig][kk] = *reinterpret_cast<const bf16x8*>(
          Zh + (size_t)(bi + ig * 16 + r) * DL + kk * 32 + kh * 8);
      bfr[ig][kk] = *reinterpret_cast<const bf16x8*>(
          Zh + (size_t)(bj + ig * 16 + r) * DL + kk * 32 + kh * 8);
    }
  f32x4 acc[4][4];
#pragma unroll
  for (int ig = 0; ig < 4; ++ig)
#pragma unroll
    for (int jg = 0; jg < 4; ++jg) {
      acc[ig][jg] = (f32x4){0.0f, 0.0f, 0.0f, 0.0f};
      acc[ig][jg] = __builtin_amdgcn_mfma_f32_16x16x32_bf16(
          afr[ig][0], bfr[jg][0], acc[ig][jg], 0, 0, 0);
      acc[ig][jg] = __builtin_amdgcn_mfma_f32_16x16x32_bf16(
          afr[ig][1], bfr[jg][1], acc[ig][jg], 0, 0, 0);
    }
#pragma unroll
  for (int ig = 0; ig < 4; ++ig)
#pragma unroll
    for (int jg = 0; jg < 4; ++jg) {
      size_t row = (size_t)(bj + jg * 16 + r);
      float4 v = make_float4(acc[ig][jg][0], acc[ig][jg][1],
                             acc[ig][jg][2], acc[ig][jg][3]);
      *reinterpret_cast<float4*>(&out[row * NN + (bi + ig * 16 + kh * 4)]) = v;
    }
}

// ---------------- launch ----------------

extern "C" void kernel_launch(void* const* d_in, const int* in_sizes, int n_in,
                              void* d_out, int out_size, void* d_ws, size_t ws_size,
                              hipStream_t stream) {
  const float* X   = (const float*)d_in[0];
  const int*   ei  = (const int*)d_in[1];
  const float* W1  = (const float*)d_in[2];
  const float* b1  = (const float*)d_in[3];
  const float* Wmu = (const float*)d_in[4];
  const float* bmu = (const float*)d_in[5];
  const float* Wk  = (const float*)d_in[6];
  const float* bk  = (const float*)d_in[7];

  char* wp = (char*)d_ws;
  auto alloc = [&](size_t bytes) -> char* {
    char* p = wp; wp += (bytes + 255) & ~(size_t)255; return p;
  };
  u32* cnt    = (u32*)alloc((size_t)NN * 4);
  u32* fill   = (u32*)alloc((size_t)NN * 4);
  u32* off    = (u32*)alloc((size_t)(NN + 1) * 4);
  u32* csr    = (u32*)alloc((size_t)NE * 4);
  float* dinv = (float*)alloc((size_t)NN * 4);
  float* XW1  = (float*)alloc((size_t)NN * DH * 4);
  float* HWmu = (float*)alloc((size_t)NN * DL * 4);
  float* HWk  = (float*)alloc((size_t)NN * 4);
  float* musr = (float*)alloc((size_t)NN * DL * 4);
  float* mus  = (float*)alloc((size_t)NN * DL * 4);
  float* kap  = (float*)alloc((size_t)NN * 4);
  float* wv   = (float*)alloc((size_t)NN * 4);
  __bf16* Zh  = (__bf16*)alloc((size_t)NN * DL * 2);

  float* outZZ = (float*)d_out;
  float* outMU = outZZ + (size_t)NN * NN;
  float* outKA = outMU + (size_t)NN * DL;

  zero_k<<<NN / 256, 256, 0, stream>>>(cnt, fill);
  count_k<<<NE / 256, 256, 0, stream>>>(ei, cnt);
  scan_k<<<1, 256, 0, stream>>>(cnt, off, dinv);
  fill_k<<<NE / 256, 256, 0, stream>>>(ei, off, fill, csr);
  sort_k<<<NN / 256, 256, 0, stream>>>(off, csr);
  mm_xw1_k<<<NN / 32, 256, 0, stream>>>(X, W1, XW1);
  agg_h_mm_k<<<NN / 8, 256, 0, stream>>>(XW1, off, csr, ei, dinv, b1, Wmu, Wk,
                                         HWmu, HWk);
  agg_mu_kap_k<<<2048 + NN / 256, 256, 0, stream>>>(HWmu, HWk, off, csr, ei, dinv,
                                                    bmu, bk, musr, kap, outKA);
  norm_sample_k<<<2048 + NN / 256, 256, 0, stream>>>(musr, mus, outMU, kap, wv);
  z_k<<<NN * DL / 256, 256, 0, stream>>>(mus, wv, Zh);
  dim3 g(64, 64);
  zzt_k<<<g, 256, 0, stream>>>(Zh, outZZ);
}